// Round 1
// baseline (209.426 us; speedup 1.0000x reference)
//
#include <hip/hip_runtime.h>
#include <math.h>

#define B_ 8
#define L_ 4096
#define DM 128
#define DI 256
#define DSN 16
#define RK 8
#define M_ (B_*L_)      // 32768 positions
#define NC 128          // number of scan chunks
#define CH 32           // chunk length (NC*CH == L_)

typedef __attribute__((ext_vector_type(8))) short bfrag;   // 8 bf16 (4 VGPRs)
typedef __attribute__((ext_vector_type(4))) float ffrag;   // 4 fp32 acc
typedef __attribute__((ext_vector_type(2))) float f32x2;   // packed-math pair

// fast silu: v_exp + v_rcp (hardware approx, ~22-bit — far above bf16 needs)
__device__ __forceinline__ float silu_f(float x) {
  return x * __builtin_amdgcn_rcpf(1.f + __expf(-x));
}
// fast softplus: v_exp + v_log instead of libm log1pf
__device__ __forceinline__ float softplus_f(float x) {
  return (x > 20.f) ? x : __logf(1.f + __expf(x));
}

__device__ __forceinline__ unsigned short f2bf(float f) {
  unsigned int u = __builtin_bit_cast(unsigned int, f);
  unsigned int r = (u + 0x7FFFu + ((u >> 16) & 1u)) >> 16;   // RNE
  return (unsigned short)r;
}
__device__ __forceinline__ unsigned int f2bf2(float lo, float hi) {
  return (unsigned int)f2bf(lo) | ((unsigned int)f2bf(hi) << 16);
}
__device__ __forceinline__ float bf2f(unsigned int us) {
  return __builtin_bit_cast(float, us << 16);
}

// ---------------------------------------------------------------------------
// in_proj bf16 MFMA GEMM, half-split + reg-prefetch W pipeline + LDS-staged
// vectorized output. Grid (2, 512): blockIdx.x = output half (0: xb, 1: zsb
// with fused silu).
// ---------------------------------------------------------------------------
__global__ __launch_bounds__(256)
void gemm_bf16_in(const float* __restrict__ A, const float* __restrict__ W,
                  unsigned short* __restrict__ xb, unsigned short* __restrict__ zsb) {
  __shared__ unsigned short As[64 * 136];   // 17.4 KB
  __shared__ unsigned short Ws[64 * 136];   // 17.4 KB
  __shared__ unsigned short Os[64 * 72];    // 9.2 KB
  const int t = threadIdx.x;
  const int m0 = blockIdx.y << 6;
  const int half = blockIdx.x;              // 0 -> xb, 1 -> zsb (silu)
  unsigned short* __restrict__ outp = half ? zsb : xb;
  const float* __restrict__ Wbase = W + (half << 8) * 128;
  for (int i = t; i < 64 * 32; i += 256) {
    int row = i >> 5, c4 = i & 31;
    float4 av = *(const float4*)&A[(m0 + row) * 128 + (c4 << 2)];
    uint2 ap = {f2bf2(av.x, av.y), f2bf2(av.z, av.w)};
    *(uint2*)&As[row * 136 + (c4 << 2)] = ap;
  }
  float4 wr[8];
#pragma unroll
  for (int k = 0; k < 8; ++k) {
    int i = t + (k << 8);
    int row = i >> 5, c4 = i & 31;
    wr[k] = *(const float4*)&Wbase[row * 128 + (c4 << 2)];
  }
#pragma unroll
  for (int k = 0; k < 8; ++k) {
    int i = t + (k << 8);
    int row = i >> 5, c4 = i & 31;
    uint2 wp = {f2bf2(wr[k].x, wr[k].y), f2bf2(wr[k].z, wr[k].w)};
    *(uint2*)&Ws[row * 136 + (c4 << 2)] = wp;
  }
  __syncthreads();
  const int w = t >> 6, l = t & 63, q = l >> 4, col = l & 15;
  for (int jt = 0; jt < 4; ++jt) {
    if (jt < 3) {
#pragma unroll
      for (int k = 0; k < 8; ++k) {
        int i = t + (k << 8);
        int row = i >> 5, c4 = i & 31;
        wr[k] = *(const float4*)&Wbase[(((jt + 1) << 6) + row) * 128 + (c4 << 2)];
      }
    }
    ffrag acc[4] = {{0.f,0.f,0.f,0.f},{0.f,0.f,0.f,0.f},{0.f,0.f,0.f,0.f},{0.f,0.f,0.f,0.f}};
#pragma unroll
    for (int s = 0; s < 4; ++s) {
      int k0 = s * 32 + q * 8;
      bfrag af = *(const bfrag*)&As[((w << 4) + col) * 136 + k0];
#pragma unroll
      for (int nt = 0; nt < 4; ++nt) {
        bfrag bf_ = *(const bfrag*)&Ws[((nt << 4) + col) * 136 + k0];
        acc[nt] = __builtin_amdgcn_mfma_f32_16x16x32_bf16(af, bf_, acc[nt], 0, 0, 0);
      }
    }
    __syncthreads();
#pragma unroll
    for (int nt = 0; nt < 4; ++nt)
#pragma unroll
      for (int i = 0; i < 4; ++i) {
        int ml = (w << 4) + (q << 2) + i;
        float v = acc[nt][i];
        if (half) v = silu_f(v);
        Os[ml * 72 + (nt << 4) + col] = f2bf(v);
      }
    if (jt < 3) {
#pragma unroll
      for (int k = 0; k < 8; ++k) {
        int i = t + (k << 8);
        int row = i >> 5, c4 = i & 31;
        uint2 wp = {f2bf2(wr[k].x, wr[k].y), f2bf2(wr[k].z, wr[k].w)};
        *(uint2*)&Ws[row * 136 + (c4 << 2)] = wp;
      }
    }
    __syncthreads();
    {
      int r = t >> 2, c8 = (t & 3) << 3;
      int m = m0 + r;
      *(uint4*)&outp[m * 256 + (jt << 6) + c8]      = *(const uint4*)&Os[r * 72 + c8];
      *(uint4*)&outp[m * 256 + (jt << 6) + 32 + c8] = *(const uint4*)&Os[r * 72 + 32 + c8];
    }
  }
}

// ---------------------------------------------------------------------------
// FUSED out_proj + LayerNorm + fc + ReLU. One block per 64-position m-tile.
// Pass 1: out_proj (2 n-tile passes, single Ws buffer). LN entirely in
// registers (row spans the 16 lanes of a quad-group; 4 shfl_xor levels).
// hnb overlays As; fcw overlays Ws. hmid never materializes (f32 in regs).
// ---------------------------------------------------------------------------
__global__ __launch_bounds__(256)
void out_ln_fc(const unsigned short* __restrict__ Yb, const float* __restrict__ W,
               const float* __restrict__ gamma, const float* __restrict__ beta,
               const float* __restrict__ fcw, float* __restrict__ out) {
  __shared__ unsigned short smA[64 * 264];    // As (yb); later hnb (stride 136)
  __shared__ unsigned short smB[128 * 136];   // Ws (stride 264, 64 rows); later fcw
  const int t = threadIdx.x;
  const int m0 = blockIdx.x << 6;
  // stage A (yb)
  for (int i = t; i < 64 * 32; i += 256) {
    int row = i >> 5, c8 = i & 31;
    uint4 av = *(const uint4*)&Yb[(m0 + row) * 256 + (c8 << 3)];
    *(uint4*)&smA[row * 264 + (c8 << 3)] = av;
  }
  const int w = t >> 6, l = t & 63, q = l >> 4, col = l & 15;
  ffrag acc[2][4];
  for (int nt2 = 0; nt2 < 2; ++nt2) {
    __syncthreads();           // smB free (iter0: covers As staging too)
    for (int i = t; i < 64 * 64; i += 256) {
      int row = i >> 6, c4 = i & 63;
      float4 wv = *(const float4*)&W[((nt2 << 6) + row) * 256 + (c4 << 2)];
      uint2 wp = {f2bf2(wv.x, wv.y), f2bf2(wv.z, wv.w)};
      *(uint2*)&smB[row * 264 + (c4 << 2)] = wp;
    }
    __syncthreads();
#pragma unroll
    for (int nt = 0; nt < 4; ++nt) acc[nt2][nt] = (ffrag){0.f, 0.f, 0.f, 0.f};
#pragma unroll
    for (int s = 0; s < 8; ++s) {
      int k0 = s * 32 + q * 8;
      bfrag af = *(const bfrag*)&smA[((w << 4) + col) * 264 + k0];
#pragma unroll
      for (int nt = 0; nt < 4; ++nt) {
        bfrag bf_ = *(const bfrag*)&smB[((nt << 4) + col) * 264 + k0];
        acc[nt2][nt] = __builtin_amdgcn_mfma_f32_16x16x32_bf16(af, bf_, acc[nt2][nt], 0, 0, 0);
      }
    }
  }
  // LN stats per row (i = 0..3); row's 128 cols live across the 16 lanes of
  // this quad-group (l = q*16 + col) with 8 values per lane.
  float mu[4], rs[4];
#pragma unroll
  for (int i = 0; i < 4; ++i) {
    float s1 = 0.f, s2 = 0.f;
#pragma unroll
    for (int nt2 = 0; nt2 < 2; ++nt2)
#pragma unroll
      for (int nt = 0; nt < 4; ++nt) {
        float v = acc[nt2][nt][i];
        s1 += v; s2 = fmaf(v, v, s2);
      }
    s1 += __shfl_xor(s1, 1); s2 += __shfl_xor(s2, 1);
    s1 += __shfl_xor(s1, 2); s2 += __shfl_xor(s2, 2);
    s1 += __shfl_xor(s1, 4); s2 += __shfl_xor(s2, 4);
    s1 += __shfl_xor(s1, 8); s2 += __shfl_xor(s2, 8);
    mu[i] = s1 * (1.f / DM);
    float var = s2 * (1.f / DM) - mu[i] * mu[i];
    rs[i] = rsqrtf(var + 1e-5f);
  }
  __syncthreads();   // all MFMA LDS reads done before overlaying smA/smB
  // normalized values -> hnb (overlay smA, stride 136)
#pragma unroll
  for (int nt2 = 0; nt2 < 2; ++nt2)
#pragma unroll
    for (int nt = 0; nt < 4; ++nt) {
      int n = (nt2 << 6) + (nt << 4) + col;
      float g = gamma[n], be = beta[n];
#pragma unroll
      for (int i = 0; i < 4; ++i) {
        int r = (w << 4) + (q << 2) + i;
        smA[r * 136 + n] = f2bf(fmaf((acc[nt2][nt][i] - mu[i]) * rs[i], g, be));
      }
    }
  // stage fcw (overlay smB, stride 136, 128 rows)
  for (int i = t; i < 128 * 32; i += 256) {
    int row = i >> 5, c4 = i & 31;
    float4 wv = *(const float4*)&fcw[row * 128 + (c4 << 2)];
    uint2 wp = {f2bf2(wv.x, wv.y), f2bf2(wv.z, wv.w)};
    *(uint2*)&smB[row * 136 + (c4 << 2)] = wp;
  }
  __syncthreads();
  // fc MFMA: wave w -> m-tile w, 8 n-tiles, K=128 (4 steps), + ReLU store
  ffrag a2[8] = {{0.f,0.f,0.f,0.f},{0.f,0.f,0.f,0.f},{0.f,0.f,0.f,0.f},{0.f,0.f,0.f,0.f},
                 {0.f,0.f,0.f,0.f},{0.f,0.f,0.f,0.f},{0.f,0.f,0.f,0.f},{0.f,0.f,0.f,0.f}};
#pragma unroll
  for (int s = 0; s < 4; ++s) {
    int k0 = s * 32 + q * 8;
    bfrag af = *(const bfrag*)&smA[((w << 4) + col) * 136 + k0];
#pragma unroll
    for (int nt = 0; nt < 8; ++nt) {
      bfrag bf_ = *(const bfrag*)&smB[((nt << 4) + col) * 136 + k0];
      a2[nt] = __builtin_amdgcn_mfma_f32_16x16x32_bf16(af, bf_, a2[nt], 0, 0, 0);
    }
  }
#pragma unroll
  for (int nt = 0; nt < 8; ++nt)
#pragma unroll
    for (int i = 0; i < 4; ++i) {
      int ml = (w << 4) + (q << 2) + i;
      out[(m0 + ml) * 128 + (nt << 4) + col] = fmaxf(a2[nt][i], 0.f);
    }
}

// ---------------------------------------------------------------------------
// Fused conv(4)+SiLU -> bf16 LDS -> MFMA x_proj -> dt_proj + softplus.
// ---------------------------------------------------------------------------
__global__ __launch_bounds__(512)
void xproj_dtproj(const unsigned short* __restrict__ xb, const float* __restrict__ xw,
                  const float* __restrict__ dtw, const float* __restrict__ dtpb,
                  const float* __restrict__ cw, const float* __restrict__ cb,
                  float* __restrict__ Bb, float* __restrict__ Cb,
                  unsigned int* __restrict__ udt) {
  __shared__ unsigned short ua[64 * 264];   // u bf16
  __shared__ unsigned short wb[48 * 264];   // xw bf16; rows 40..47 zeroed
  __shared__ float dtr_s[64 * 12];
  const int t = threadIdx.x;
  const int p0 = blockIdx.x << 6;
  {
    const int k = t & 255, half = t >> 8;
    const int pstart = half << 5;
    const int base = p0 + pstart;
    const int lb = base & (L_ - 1);
    const float w0 = cw[k*4], w1 = cw[k*4+1], w2 = cw[k*4+2], w3 = cw[k*4+3];
    const float bias = cb[k];
    float x0 = (lb >= 3) ? bf2f((unsigned int)xb[(base - 3) * 256 + k]) : 0.f;
    float x1 = (lb >= 2) ? bf2f((unsigned int)xb[(base - 2) * 256 + k]) : 0.f;
    float x2 = (lb >= 1) ? bf2f((unsigned int)xb[(base - 1) * 256 + k]) : 0.f;
#pragma unroll 8
    for (int it = 0; it < 32; ++it) {
      float x3 = bf2f((unsigned int)xb[(base + it) * 256 + k]);
      float u = silu_f(fmaf(w0, x0, fmaf(w1, x1, fmaf(w2, x2, fmaf(w3, x3, bias)))));
      ua[(pstart + it) * 264 + k] = f2bf(u);
      x0 = x1; x1 = x2; x2 = x3;
    }
  }
  for (int i = t; i < 40 * 256; i += 512) {
    int n = i >> 8, k = i & 255;
    wb[n * 264 + k] = f2bf(xw[i]);
  }
  for (int i = t; i < 8 * 264; i += 512) wb[40 * 264 + i] = 0;
  __syncthreads();
  const int w = t >> 6, l = t & 63, q = l >> 4, col = l & 15;
  for (int tile = w; tile < 12; tile += 8) {
    const int mt = tile & 3, nt = tile >> 2;
    ffrag acc = {0.f, 0.f, 0.f, 0.f};
#pragma unroll
    for (int s = 0; s < 8; ++s) {
      int k0 = s * 32 + q * 8;
      bfrag af = *(const bfrag*)&ua[((mt << 4) + col) * 264 + k0];
      bfrag bf_ = *(const bfrag*)&wb[((nt << 4) + col) * 264 + k0];
      acc = __builtin_amdgcn_mfma_f32_16x16x32_bf16(af, bf_, acc, 0, 0, 0);
    }
#pragma unroll
    for (int i = 0; i < 4; ++i) {
      int ml = (mt << 4) + (q << 2) + i;
      int m = p0 + ml;
      if (nt == 0) {
        if (col < 8) dtr_s[ml * 12 + col] = acc[i];
        else         Bb[m * 16 + (col - 8)] = acc[i];
      } else if (nt == 1) {
        if (col < 8) Bb[m * 16 + 8 + col] = acc[i];
        else         Cb[m * 16 + (col - 8)] = acc[i];
      } else {
        if (col < 8) Cb[m * 16 + 8 + col] = acc[i];
      }
    }
  }
  __syncthreads();
  {
    const int d = t & 255, half = t >> 8;
    const int pstart = half << 5;
    float w8[8];
    *(float4*)&w8[0] = *(const float4*)&dtw[d * 8];
    *(float4*)&w8[4] = *(const float4*)&dtw[d * 8 + 4];
    const float bias = dtpb[d];
#pragma unroll 4
    for (int pp = pstart; pp < pstart + 32; ++pp) {
      float r0[8];
      *(float4*)&r0[0] = *(const float4*)&dtr_s[pp * 12];
      *(float4*)&r0[4] = *(const float4*)&dtr_s[pp * 12 + 4];
      float a2 = bias;
#pragma unroll
      for (int r2 = 0; r2 < 8; ++r2) a2 = fmaf(r0[r2], w8[r2], a2);
      float sp = softplus_f(a2);
      udt[(p0 + pp) * 256 + d] =
          (unsigned int)ua[pp * 264 + d] | ((unsigned int)f2bf(sp) << 16);
    }
  }
}

// ---------------------------------------------------------------------------
// Scan phase 1 (CH=32): B staged to LDS; udt chunk bulk-staged to LDS
// (coalesced uint4, latency paid once — replaces per-iteration 4B global
// loads with prefetch depth 2); cP/cHe bf16.
// LDS: 2 KB (Bs) + 32 KB (Us) = 34 KB -> still 2 blocks/CU at 512 thr.
// ---------------------------------------------------------------------------
__global__ __launch_bounds__(512, 4)
void scan_phase1(const unsigned int* __restrict__ udt,
                 const float* __restrict__ Bb, const float* __restrict__ alog,
                 unsigned short* __restrict__ cP, unsigned short* __restrict__ cHe) {
  __shared__ float Bs[CH * 16];          // 2 KB
  __shared__ unsigned int Us[CH * 256];  // 32 KB (whole-chunk udt)
  const int bc = blockIdx.x;
  const int b = bc >> 7, c = bc & (NC - 1);
  const int t = threadIdx.x;
  const int l = t & 63, w = t >> 6;
  const int d = (w << 5) + (l & 31);
  const int sh = l >> 5;
  const int soff = sh << 3;
  const int base = b * L_ + c * CH;
  if (t < CH * 4) ((float4*)Bs)[t] = *(const float4*)&Bb[base * 16 + (t << 2)];
  // bulk-stage udt chunk: 32x256 uints = 2048 uint4, 4 per thread, coalesced
#pragma unroll
  for (int k = 0; k < 4; ++k) {
    int i = t + (k << 9);
    ((uint4*)Us)[i] = *(const uint4*)&udt[base * 256 + (i << 2)];
  }
  float a[8];
  bool okl = true;
#pragma unroll
  for (int j = 0; j < 8; ++j) {
    a[j] = -__expf(alog[d * 16 + soff + j]);
    float tgt = (float)(soff + j + 1);
    okl = okl && (fabsf(a[j] + tgt) <= 1e-3f * tgt);
  }
  const bool fast = (bool)__all((int)okl);
  f32x2 h2[4] = {{0.f,0.f},{0.f,0.f},{0.f,0.f},{0.f,0.f}};
  float sdt = 0.f;
  __syncthreads();
#pragma unroll 4
  for (int ll = 0; ll < CH; ++ll) {
    unsigned int wv0 = Us[ll * 256 + d];   // broadcast within half-waves, conflict-free
    float4 b0 = *(const float4*)&Bs[ll * 16 + soff];
    float4 b1 = *(const float4*)&Bs[ll * 16 + soff + 4];
    float uv  = bf2f(wv0 & 0xFFFFu);
    float dtv = bf2f(wv0 >> 16);
    f32x2 B2[4] = {{b0.x,b0.y},{b0.z,b0.w},{b1.x,b1.y},{b1.z,b1.w}};
    float du = dtv * uv;
    sdt += dtv;
    if (fast) {
      float e1 = __expf(-dtv);
      float e2 = e1 * e1, e4 = e2 * e2, e8 = e4 * e4;
      float st = sh ? e8 * e1 : e1;
      f32x2 dA = {st, st * e1};
      f32x2 e22 = {e2, e2};
      f32x2 du2 = {du, du};
#pragma unroll
      for (int j = 0; j < 4; ++j) {
        h2[j] = dA * h2[j] + du2 * B2[j];
        dA = dA * e22;
      }
    } else {
#pragma unroll
      for (int j = 0; j < 8; ++j) {
        float dA = __expf(dtv * a[j]);
        h2[j >> 1][j & 1] = fmaf(dA, h2[j >> 1][j & 1], du * B2[j >> 1][j & 1]);
      }
    }
  }
#pragma unroll
  for (int j = 0; j < 8; ++j) {
    int o = (bc * 16 + soff + j) * 256 + d;
    cP[o]  = f2bf(__expf(a[j] * sdt));
    cHe[o] = f2bf(h2[j >> 1][j & 1]);
  }
}

// ---------------------------------------------------------------------------
// Hierarchical combine (NC=128, bf16): 512 thr = 64 sd x 8 segments of 16.
// ---------------------------------------------------------------------------
__global__ __launch_bounds__(512)
void scan_combine(unsigned short* __restrict__ cP, const unsigned short* __restrict__ cHe) {
  __shared__ float segP[64 * 9], segH[64 * 9], segS[64 * 9];
  const int t = threadIdx.x;
  const int sdl = t & 63, seg = t >> 6;
  const int blk = blockIdx.x;
  const int b = blk >> 6, grp = blk & 63;
  const int sd = (grp << 6) + sdl;
  const int base = b * NC * 4096 + sd;
  float Pacc = 1.f, Hacc = 0.f;
#pragma unroll
  for (int i = 0; i < 16; ++i) {
    int idx = base + (seg * 16 + i) * 4096;
    float p = bf2f((unsigned int)cP[idx]);
    float he = bf2f((unsigned int)cHe[idx]);
    Hacc = fmaf(p, Hacc, he);
    Pacc *= p;
  }
  segP[sdl * 9 + seg] = Pacc;
  segH[sdl * 9 + seg] = Hacc;
  __syncthreads();
  if (t < 64) {
    float hs = 0.f;
#pragma unroll
    for (int s2 = 0; s2 < 8; ++s2) {
      segS[t * 9 + s2] = hs;
      hs = fmaf(segP[t * 9 + s2], hs, segH[t * 9 + s2]);
    }
  }
  __syncthreads();
  float hs = segS[sdl * 9 + seg];
#pragma unroll
  for (int i = 0; i < 16; ++i) {
    int idx = base + (seg * 16 + i) * 4096;
    float p = bf2f((unsigned int)cP[idx]);
    float he = bf2f((unsigned int)cHe[idx]);
    cP[idx] = f2bf(hs);
    hs = fmaf(p, hs, he);
  }
}

// ---------------------------------------------------------------------------
// Scan phase 3 (CH=32): B/C staged to LDS; udt AND zsb chunk bulk-staged to
// LDS (coalesced uint4, latency paid once); h_start read bf16; gated y bf16.
// LDS: 2+2 (Bs/Cs) + 32 (Us) + 16 (Zs) = 52 KB -> still 2 blocks/CU.
// ---------------------------------------------------------------------------
__global__ __launch_bounds__(512, 4)
void scan_phase3(const unsigned int* __restrict__ udt,
                 const float* __restrict__ Bb, const float* __restrict__ Cb,
                 const float* __restrict__ alog, const unsigned short* __restrict__ hst,
                 const float* __restrict__ dsk,
                 const unsigned short* __restrict__ zsb,
                 unsigned short* __restrict__ yb) {
  __shared__ float Bs[CH * 16];            // 2 KB
  __shared__ float Cs[CH * 16];            // 2 KB
  __shared__ unsigned int Us[CH * 256];    // 32 KB (whole-chunk udt)
  __shared__ unsigned short Zs[CH * 256];  // 16 KB (whole-chunk zsb)
  const int bc = blockIdx.x;
  const int b = bc >> 7, c = bc & (NC - 1);
  const int t = threadIdx.x;
  const int l = t & 63, w = t >> 6;
  const int d = (w << 5) + (l & 31);
  const int sh = l >> 5;
  const int soff = sh << 3;
  const int base = b * L_ + c * CH;
  if (t < CH * 4)            ((float4*)Bs)[t]            = *(const float4*)&Bb[base * 16 + (t << 2)];
  else if (t < CH * 8)       ((float4*)Cs)[t - CH * 4]   = *(const float4*)&Cb[base * 16 + ((t - CH * 4) << 2)];
  // bulk-stage udt chunk: 2048 uint4, 4 per thread
#pragma unroll
  for (int k = 0; k < 4; ++k) {
    int i = t + (k << 9);
    ((uint4*)Us)[i] = *(const uint4*)&udt[base * 256 + (i << 2)];
  }
  // bulk-stage zsb chunk: 32x256 shorts = 1024 uint4, 2 per thread
#pragma unroll
  for (int k = 0; k < 2; ++k) {
    int i = t + (k << 9);
    ((uint4*)Zs)[i] = *(const uint4*)&zsb[base * 256 + (i << 3)];
  }
  float a[8];
  bool okl = true;
#pragma unroll
  for (int j = 0; j < 8; ++j) {
    a[j] = -__expf(alog[d * 16 + soff + j]);
    float tgt = (float)(soff + j + 1);
    okl = okl && (fabsf(a[j] + tgt) <= 1e-3f * tgt);
  }
  const bool fast = (bool)__all((int)okl);
  const float dskv = dsk[d];
  f32x2 h2[4];
#pragma unroll
  for (int j = 0; j < 8; ++j)
    h2[j >> 1][j & 1] = bf2f((unsigned int)hst[(bc * 16 + soff + j) * 256 + d]);
  __syncthreads();
#pragma unroll 4
  for (int ll = 0; ll < CH; ++ll) {
    const int m = base + ll;
    unsigned int wv0 = Us[ll * 256 + d];       // broadcast, conflict-free
    unsigned short zv0 = Zs[ll * 256 + d];
    float4 b0 = *(const float4*)&Bs[ll * 16 + soff];
    float4 b1 = *(const float4*)&Bs[ll * 16 + soff + 4];
    float4 c0 = *(const float4*)&Cs[ll * 16 + soff];
    float4 c1 = *(const float4*)&Cs[ll * 16 + soff + 4];
    float uv  = bf2f(wv0 & 0xFFFFu);
    float dtv = bf2f(wv0 >> 16);
    f32x2 B2[4] = {{b0.x,b0.y},{b0.z,b0.w},{b1.x,b1.y},{b1.z,b1.w}};
    f32x2 C2[4] = {{c0.x,c0.y},{c0.z,c0.w},{c1.x,c1.y},{c1.z,c1.w}};
    float du = dtv * uv;
    f32x2 y2 = {0.f, 0.f};
    if (fast) {
      float e1 = __expf(-dtv);
      float e2 = e1 * e1, e4 = e2 * e2, e8 = e4 * e4;
      float st = sh ? e8 * e1 : e1;
      f32x2 dA = {st, st * e1};
      f32x2 e22 = {e2, e2};
      f32x2 du2 = {du, du};
#pragma unroll
      for (int j = 0; j < 4; ++j) {
        h2[j] = dA * h2[j] + du2 * B2[j];
        y2 = y2 + h2[j] * C2[j];
        dA = dA * e22;
      }
    } else {
#pragma unroll
      for (int j = 0; j < 8; ++j) {
        float dA = __expf(dtv * a[j]);
        float hh = fmaf(dA, h2[j >> 1][j & 1], du * B2[j >> 1][j & 1]);
        h2[j >> 1][j & 1] = hh;
        y2[j & 1] = fmaf(hh, C2[j >> 1][j & 1], y2[j & 1]);
      }
    }
    float y = y2.x + y2.y;
    y += __shfl_xor(y, 32);
    if (sh == 0) {
      float zs = bf2f((unsigned int)zv0);
      yb[m * 256 + d] = f2bf(fmaf(uv, dskv, y) * zs);
    }
  }
}

extern "C" void kernel_launch(void* const* d_in, const int* in_sizes, int n_in,
                              void* d_out, int out_size, void* d_ws, size_t ws_size,
                              hipStream_t stream) {
  (void)in_sizes; (void)n_in; (void)out_size; (void)ws_size;
  const float* s    = (const float*)d_in[0];
  const float* w_in = (const float*)d_in[1];
  const float* cw   = (const float*)d_in[2];
  const float* cb   = (const float*)d_in[3];
  const float* xw   = (const float*)d_in[4];
  const float* dtw  = (const float*)d_in[5];
  const float* dtpb = (const float*)d_in[6];
  const float* alog = (const float*)d_in[7];
  const float* dsk  = (const float*)d_in[8];
  const float* ow   = (const float*)d_in[9];
  const float* gam  = (const float*)d_in[10];
  const float* bet  = (const float*)d_in[11];
  const float* fcw  = (const float*)d_in[12];
  float* out = (float*)d_out;
  float* ws  = (float*)d_ws;

  // float-unit offsets; all regions disjoint (audited):
  unsigned short* xb   = (unsigned short*)ws;                 // [0, 4194304)
  unsigned short* zsb  = (unsigned short*)(ws + 4194304);     // [4194304, 8388608)
  unsigned int*   udt  = (unsigned int*)(ws + 8388608);       // [8388608, 16777216)
  float*          Bb   = ws + 16777216;                       // [16777216, 17301504)
  float*          Cb   = ws + 17301504;                       // [17301504, 17825792)
  unsigned short* cP   = (unsigned short*)(ws + 17825792);    // [17825792, 19922944)
  unsigned short* cHe  = (unsigned short*)(ws + 19922944);    // [19922944, 22020096)
  unsigned short* yb   = (unsigned short*)(ws + 22020096);    // [22020096, 26214400)

  // 1. in_proj (bf16 MFMA, half-split + W pipeline): x -> xb, z -> silu -> zsb
  gemm_bf16_in<<<dim3(2, 512), 256, 0, stream>>>(s, w_in, xb, zsb);
  // 2. fused conv/silu + x_proj (MFMA) + dt_proj (fast softplus); emits udt
  xproj_dtproj<<<512, 512, 0, stream>>>(xb, xw, dtw, dtpb, cw, cb, Bb, Cb, udt);
  // 3-5. chunked selective scan (CH=32, bf16 intermediates, LDS-staged udt/zsb)
  scan_phase1<<<B_ * NC, 512, 0, stream>>>(udt, Bb, alog, cP, cHe);
  scan_combine<<<512, 512, 0, stream>>>(cP, cHe);
  scan_phase3<<<B_ * NC, 512, 0, stream>>>(udt, Bb, Cb, alog, cP, dsk, zsb, yb);
  // 6. FUSED out_proj + LayerNorm + fc + ReLU (hmid never materializes)
  out_ln_fc<<<512, 256, 0, stream>>>(yb, ow, gam, bet, fcw, out);
}

// Round 2
// 185.990 us; speedup vs baseline: 1.1260x; 1.1260x over previous
//
#include <hip/hip_runtime.h>
#include <math.h>

#define B_ 8
#define L_ 4096
#define DM 128
#define DI 256
#define DSN 16
#define RK 8
#define M_ (B_*L_)      // 32768 positions
#define NC 128          // number of scan chunks
#define CH 32           // chunk length (NC*CH == L_)
#define CH2 64          // fused phase3 tile: 2 chunks

typedef __attribute__((ext_vector_type(8))) short bfrag;   // 8 bf16 (4 VGPRs)
typedef __attribute__((ext_vector_type(4))) float ffrag;   // 4 fp32 acc
typedef __attribute__((ext_vector_type(2))) float f32x2;   // packed-math pair

// fast silu: v_exp + v_rcp (hardware approx, ~22-bit — far above bf16 needs)
__device__ __forceinline__ float silu_f(float x) {
  return x * __builtin_amdgcn_rcpf(1.f + __expf(-x));
}
// fast softplus: v_exp + v_log instead of libm log1pf
__device__ __forceinline__ float softplus_f(float x) {
  return (x > 20.f) ? x : __logf(1.f + __expf(x));
}

__device__ __forceinline__ unsigned short f2bf(float f) {
  unsigned int u = __builtin_bit_cast(unsigned int, f);
  unsigned int r = (u + 0x7FFFu + ((u >> 16) & 1u)) >> 16;   // RNE
  return (unsigned short)r;
}
__device__ __forceinline__ unsigned int f2bf2(float lo, float hi) {
  return (unsigned int)f2bf(lo) | ((unsigned int)f2bf(hi) << 16);
}
__device__ __forceinline__ float bf2f(unsigned int us) {
  return __builtin_bit_cast(float, us << 16);
}

// ---------------------------------------------------------------------------
// in_proj bf16 MFMA GEMM, half-split + reg-prefetch W pipeline + LDS-staged
// vectorized output. Grid (2, 512): blockIdx.x = output half (0: xb, 1: zsb
// with fused silu).
// ---------------------------------------------------------------------------
__global__ __launch_bounds__(256)
void gemm_bf16_in(const float* __restrict__ A, const float* __restrict__ W,
                  unsigned short* __restrict__ xb, unsigned short* __restrict__ zsb) {
  __shared__ unsigned short As[64 * 136];   // 17.4 KB
  __shared__ unsigned short Ws[64 * 136];   // 17.4 KB
  __shared__ unsigned short Os[64 * 72];    // 9.2 KB
  const int t = threadIdx.x;
  const int m0 = blockIdx.y << 6;
  const int half = blockIdx.x;              // 0 -> xb, 1 -> zsb (silu)
  unsigned short* __restrict__ outp = half ? zsb : xb;
  const float* __restrict__ Wbase = W + (half << 8) * 128;
  for (int i = t; i < 64 * 32; i += 256) {
    int row = i >> 5, c4 = i & 31;
    float4 av = *(const float4*)&A[(m0 + row) * 128 + (c4 << 2)];
    uint2 ap = {f2bf2(av.x, av.y), f2bf2(av.z, av.w)};
    *(uint2*)&As[row * 136 + (c4 << 2)] = ap;
  }
  float4 wr[8];
#pragma unroll
  for (int k = 0; k < 8; ++k) {
    int i = t + (k << 8);
    int row = i >> 5, c4 = i & 31;
    wr[k] = *(const float4*)&Wbase[row * 128 + (c4 << 2)];
  }
#pragma unroll
  for (int k = 0; k < 8; ++k) {
    int i = t + (k << 8);
    int row = i >> 5, c4 = i & 31;
    uint2 wp = {f2bf2(wr[k].x, wr[k].y), f2bf2(wr[k].z, wr[k].w)};
    *(uint2*)&Ws[row * 136 + (c4 << 2)] = wp;
  }
  __syncthreads();
  const int w = t >> 6, l = t & 63, q = l >> 4, col = l & 15;
  for (int jt = 0; jt < 4; ++jt) {
    if (jt < 3) {
#pragma unroll
      for (int k = 0; k < 8; ++k) {
        int i = t + (k << 8);
        int row = i >> 5, c4 = i & 31;
        wr[k] = *(const float4*)&Wbase[(((jt + 1) << 6) + row) * 128 + (c4 << 2)];
      }
    }
    ffrag acc[4] = {{0.f,0.f,0.f,0.f},{0.f,0.f,0.f,0.f},{0.f,0.f,0.f,0.f},{0.f,0.f,0.f,0.f}};
#pragma unroll
    for (int s = 0; s < 4; ++s) {
      int k0 = s * 32 + q * 8;
      bfrag af = *(const bfrag*)&As[((w << 4) + col) * 136 + k0];
#pragma unroll
      for (int nt = 0; nt < 4; ++nt) {
        bfrag bf_ = *(const bfrag*)&Ws[((nt << 4) + col) * 136 + k0];
        acc[nt] = __builtin_amdgcn_mfma_f32_16x16x32_bf16(af, bf_, acc[nt], 0, 0, 0);
      }
    }
    __syncthreads();
#pragma unroll
    for (int nt = 0; nt < 4; ++nt)
#pragma unroll
      for (int i = 0; i < 4; ++i) {
        int ml = (w << 4) + (q << 2) + i;
        float v = acc[nt][i];
        if (half) v = silu_f(v);
        Os[ml * 72 + (nt << 4) + col] = f2bf(v);
      }
    if (jt < 3) {
#pragma unroll
      for (int k = 0; k < 8; ++k) {
        int i = t + (k << 8);
        int row = i >> 5, c4 = i & 31;
        uint2 wp = {f2bf2(wr[k].x, wr[k].y), f2bf2(wr[k].z, wr[k].w)};
        *(uint2*)&Ws[row * 136 + (c4 << 2)] = wp;
      }
    }
    __syncthreads();
    {
      int r = t >> 2, c8 = (t & 3) << 3;
      int m = m0 + r;
      *(uint4*)&outp[m * 256 + (jt << 6) + c8]      = *(const uint4*)&Os[r * 72 + c8];
      *(uint4*)&outp[m * 256 + (jt << 6) + 32 + c8] = *(const uint4*)&Os[r * 72 + 32 + c8];
    }
  }
}

// ---------------------------------------------------------------------------
// Fused conv(4)+SiLU -> bf16 LDS -> MFMA x_proj -> dt_proj + softplus.
// ---------------------------------------------------------------------------
__global__ __launch_bounds__(512)
void xproj_dtproj(const unsigned short* __restrict__ xb, const float* __restrict__ xw,
                  const float* __restrict__ dtw, const float* __restrict__ dtpb,
                  const float* __restrict__ cw, const float* __restrict__ cb,
                  float* __restrict__ Bb, float* __restrict__ Cb,
                  unsigned int* __restrict__ udt) {
  __shared__ unsigned short ua[64 * 264];   // u bf16
  __shared__ unsigned short wb[48 * 264];   // xw bf16; rows 40..47 zeroed
  __shared__ float dtr_s[64 * 12];
  const int t = threadIdx.x;
  const int p0 = blockIdx.x << 6;
  {
    const int k = t & 255, half = t >> 8;
    const int pstart = half << 5;
    const int base = p0 + pstart;
    const int lb = base & (L_ - 1);
    const float w0 = cw[k*4], w1 = cw[k*4+1], w2 = cw[k*4+2], w3 = cw[k*4+3];
    const float bias = cb[k];
    float x0 = (lb >= 3) ? bf2f((unsigned int)xb[(base - 3) * 256 + k]) : 0.f;
    float x1 = (lb >= 2) ? bf2f((unsigned int)xb[(base - 2) * 256 + k]) : 0.f;
    float x2 = (lb >= 1) ? bf2f((unsigned int)xb[(base - 1) * 256 + k]) : 0.f;
#pragma unroll 8
    for (int it = 0; it < 32; ++it) {
      float x3 = bf2f((unsigned int)xb[(base + it) * 256 + k]);
      float u = silu_f(fmaf(w0, x0, fmaf(w1, x1, fmaf(w2, x2, fmaf(w3, x3, bias)))));
      ua[(pstart + it) * 264 + k] = f2bf(u);
      x0 = x1; x1 = x2; x2 = x3;
    }
  }
  for (int i = t; i < 40 * 256; i += 512) {
    int n = i >> 8, k = i & 255;
    wb[n * 264 + k] = f2bf(xw[i]);
  }
  for (int i = t; i < 8 * 264; i += 512) wb[40 * 264 + i] = 0;
  __syncthreads();
  const int w = t >> 6, l = t & 63, q = l >> 4, col = l & 15;
  for (int tile = w; tile < 12; tile += 8) {
    const int mt = tile & 3, nt = tile >> 2;
    ffrag acc = {0.f, 0.f, 0.f, 0.f};
#pragma unroll
    for (int s = 0; s < 8; ++s) {
      int k0 = s * 32 + q * 8;
      bfrag af = *(const bfrag*)&ua[((mt << 4) + col) * 264 + k0];
      bfrag bf_ = *(const bfrag*)&wb[((nt << 4) + col) * 264 + k0];
      acc = __builtin_amdgcn_mfma_f32_16x16x32_bf16(af, bf_, acc, 0, 0, 0);
    }
#pragma unroll
    for (int i = 0; i < 4; ++i) {
      int ml = (mt << 4) + (q << 2) + i;
      int m = p0 + ml;
      if (nt == 0) {
        if (col < 8) dtr_s[ml * 12 + col] = acc[i];
        else         Bb[m * 16 + (col - 8)] = acc[i];
      } else if (nt == 1) {
        if (col < 8) Bb[m * 16 + 8 + col] = acc[i];
        else         Cb[m * 16 + (col - 8)] = acc[i];
      } else {
        if (col < 8) Cb[m * 16 + 8 + col] = acc[i];
      }
    }
  }
  __syncthreads();
  {
    const int d = t & 255, half = t >> 8;
    const int pstart = half << 5;
    float w8[8];
    *(float4*)&w8[0] = *(const float4*)&dtw[d * 8];
    *(float4*)&w8[4] = *(const float4*)&dtw[d * 8 + 4];
    const float bias = dtpb[d];
#pragma unroll 4
    for (int pp = pstart; pp < pstart + 32; ++pp) {
      float r0[8];
      *(float4*)&r0[0] = *(const float4*)&dtr_s[pp * 12];
      *(float4*)&r0[4] = *(const float4*)&dtr_s[pp * 12 + 4];
      float a2 = bias;
#pragma unroll
      for (int r2 = 0; r2 < 8; ++r2) a2 = fmaf(r0[r2], w8[r2], a2);
      float sp = softplus_f(a2);
      udt[(p0 + pp) * 256 + d] =
          (unsigned int)ua[pp * 264 + d] | ((unsigned int)f2bf(sp) << 16);
    }
  }
}

// ---------------------------------------------------------------------------
// Scan phase 1 (CH=32): B staged to LDS; udt prefetch depth 2; cP/cHe bf16.
// (reverted to prefetch structure — bulk LDS staging regressed in round 0)
// ---------------------------------------------------------------------------
__global__ __launch_bounds__(512, 4)
void scan_phase1(const unsigned int* __restrict__ udt,
                 const float* __restrict__ Bb, const float* __restrict__ alog,
                 unsigned short* __restrict__ cP, unsigned short* __restrict__ cHe) {
  __shared__ float Bs[CH * 16];   // 2 KB
  const int bc = blockIdx.x;
  const int b = bc >> 7, c = bc & (NC - 1);
  const int t = threadIdx.x;
  const int l = t & 63, w = t >> 6;
  const int d = (w << 5) + (l & 31);
  const int sh = l >> 5;
  const int soff = sh << 3;
  const int base = b * L_ + c * CH;
  if (t < CH * 4) ((float4*)Bs)[t] = *(const float4*)&Bb[base * 16 + (t << 2)];
  float a[8];
  bool okl = true;
#pragma unroll
  for (int j = 0; j < 8; ++j) {
    a[j] = -__expf(alog[d * 16 + soff + j]);
    float tgt = (float)(soff + j + 1);
    okl = okl && (fabsf(a[j] + tgt) <= 1e-3f * tgt);
  }
  const bool fast = (bool)__all((int)okl);
  f32x2 h2[4] = {{0.f,0.f},{0.f,0.f},{0.f,0.f},{0.f,0.f}};
  float sdt = 0.f;
  unsigned int wv0 = udt[base * 256 + d];
  unsigned int wv1 = udt[(base + 1) * 256 + d];
  __syncthreads();
#pragma unroll 4
  for (int ll = 0; ll < CH; ++ll) {
    const int m2 = base + ((ll + 2 < CH) ? ll + 2 : CH - 1);
    unsigned int wv2 = udt[m2 * 256 + d];
    float4 b0 = *(const float4*)&Bs[ll * 16 + soff];
    float4 b1 = *(const float4*)&Bs[ll * 16 + soff + 4];
    float uv  = bf2f(wv0 & 0xFFFFu);
    float dtv = bf2f(wv0 >> 16);
    f32x2 B2[4] = {{b0.x,b0.y},{b0.z,b0.w},{b1.x,b1.y},{b1.z,b1.w}};
    float du = dtv * uv;
    sdt += dtv;
    if (fast) {
      float e1 = __expf(-dtv);
      float e2 = e1 * e1, e4 = e2 * e2, e8 = e4 * e4;
      float st = sh ? e8 * e1 : e1;
      f32x2 dA = {st, st * e1};
      f32x2 e22 = {e2, e2};
      f32x2 du2 = {du, du};
#pragma unroll
      for (int j = 0; j < 4; ++j) {
        h2[j] = dA * h2[j] + du2 * B2[j];
        dA = dA * e22;
      }
    } else {
#pragma unroll
      for (int j = 0; j < 8; ++j) {
        float dA = __expf(dtv * a[j]);
        h2[j >> 1][j & 1] = fmaf(dA, h2[j >> 1][j & 1], du * B2[j >> 1][j & 1]);
      }
    }
    wv0 = wv1; wv1 = wv2;
  }
#pragma unroll
  for (int j = 0; j < 8; ++j) {
    int o = (bc * 16 + soff + j) * 256 + d;
    cP[o]  = f2bf(__expf(a[j] * sdt));
    cHe[o] = f2bf(h2[j >> 1][j & 1]);
  }
}

// ---------------------------------------------------------------------------
// Hierarchical combine (NC=128, bf16): 512 thr = 64 sd x 8 segments of 16.
// ---------------------------------------------------------------------------
__global__ __launch_bounds__(512)
void scan_combine(unsigned short* __restrict__ cP, const unsigned short* __restrict__ cHe) {
  __shared__ float segP[64 * 9], segH[64 * 9], segS[64 * 9];
  const int t = threadIdx.x;
  const int sdl = t & 63, seg = t >> 6;
  const int blk = blockIdx.x;
  const int b = blk >> 6, grp = blk & 63;
  const int sd = (grp << 6) + sdl;
  const int base = b * NC * 4096 + sd;
  float Pacc = 1.f, Hacc = 0.f;
#pragma unroll
  for (int i = 0; i < 16; ++i) {
    int idx = base + (seg * 16 + i) * 4096;
    float p = bf2f((unsigned int)cP[idx]);
    float he = bf2f((unsigned int)cHe[idx]);
    Hacc = fmaf(p, Hacc, he);
    Pacc *= p;
  }
  segP[sdl * 9 + seg] = Pacc;
  segH[sdl * 9 + seg] = Hacc;
  __syncthreads();
  if (t < 64) {
    float hs = 0.f;
#pragma unroll
    for (int s2 = 0; s2 < 8; ++s2) {
      segS[t * 9 + s2] = hs;
      hs = fmaf(segP[t * 9 + s2], hs, segH[t * 9 + s2]);
    }
  }
  __syncthreads();
  float hs = segS[sdl * 9 + seg];
#pragma unroll
  for (int i = 0; i < 16; ++i) {
    int idx = base + (seg * 16 + i) * 4096;
    float p = bf2f((unsigned int)cP[idx]);
    float he = bf2f((unsigned int)cHe[idx]);
    cP[idx] = f2bf(hs);
    hs = fmaf(p, hs, he);
  }
}

// ---------------------------------------------------------------------------
// FUSED scan phase 3 + out_proj + LayerNorm + fc + ReLU.
// Block = 64 positions (2 scan chunks; h_start read once for the first chunk,
// recurrence continued in f32 across the boundary — strictly more accurate).
// Gated y goes straight to LDS (64x264 bf16, same layout out_ln_fc staged),
// then the out_proj->LN->fc->ReLU epilogue runs in-kernel (waves 0-3).
// Deletes the yb HBM round-trip (33.6 MB) and one kernel launch.
// LDS: Bs 4K + Cs 4K + ya 33.8K + smB 34.8K = 76.6 KB -> 2 blocks/CU.
// ---------------------------------------------------------------------------
__global__ __launch_bounds__(512, 4)
void scan3_out_ln_fc(const unsigned int* __restrict__ udt,
                     const float* __restrict__ Bb, const float* __restrict__ Cb,
                     const float* __restrict__ alog, const unsigned short* __restrict__ hst,
                     const float* __restrict__ dsk,
                     const unsigned short* __restrict__ zsb,
                     const float* __restrict__ W,
                     const float* __restrict__ gamma, const float* __restrict__ beta,
                     const float* __restrict__ fcw, float* __restrict__ out) {
  __shared__ float Bs[CH2 * 16];             // 4 KB
  __shared__ float Cs[CH2 * 16];             // 4 KB
  __shared__ unsigned short smA[64 * 264];   // ya (stride 264); later hnb (stride 136)
  __shared__ unsigned short smB[128 * 136];  // ow halves (stride 264); later fcw (136)
  const int bc = blockIdx.x;
  const int b = bc >> 6, cc = bc & 63;
  const int t = threadIdx.x;
  const int l = t & 63, w = t >> 6;
  const int d = (w << 5) + (l & 31);
  const int sh = l >> 5;
  const int soff = sh << 3;
  const int base = b * L_ + (cc << 1) * CH;   // 64-position tile start
  const int hc = b * NC + (cc << 1);          // h_start chunk index
  // stage B (threads 0-255) and C (threads 256-511): 64x16 floats each
  if (t < CH2 * 4)           ((float4*)Bs)[t]            = *(const float4*)&Bb[base * 16 + (t << 2)];
  else if (t < CH2 * 8)      ((float4*)Cs)[t - CH2 * 4]  = *(const float4*)&Cb[base * 16 + ((t - CH2 * 4) << 2)];
  float a[8];
  bool okl = true;
#pragma unroll
  for (int j = 0; j < 8; ++j) {
    a[j] = -__expf(alog[d * 16 + soff + j]);
    float tgt = (float)(soff + j + 1);
    okl = okl && (fabsf(a[j] + tgt) <= 1e-3f * tgt);
  }
  const bool fast = (bool)__all((int)okl);
  const float dskv = dsk[d];
  f32x2 h2[4];
#pragma unroll
  for (int j = 0; j < 8; ++j)
    h2[j >> 1][j & 1] = bf2f((unsigned int)hst[(hc * 16 + soff + j) * 256 + d]);
  unsigned int wv0 = udt[base * 256 + d];
  unsigned int wv1 = udt[(base + 1) * 256 + d];
  unsigned short zv0 = zsb[base * 256 + d];
  unsigned short zv1 = zsb[(base + 1) * 256 + d];
  __syncthreads();
#pragma unroll 4
  for (int ll = 0; ll < CH2; ++ll) {
    const int m2 = base + ((ll + 2 < CH2) ? ll + 2 : CH2 - 1);
    unsigned int wv2 = udt[m2 * 256 + d];
    unsigned short zv2 = zsb[m2 * 256 + d];
    float4 b0 = *(const float4*)&Bs[ll * 16 + soff];
    float4 b1 = *(const float4*)&Bs[ll * 16 + soff + 4];
    float4 c0 = *(const float4*)&Cs[ll * 16 + soff];
    float4 c1 = *(const float4*)&Cs[ll * 16 + soff + 4];
    float uv  = bf2f(wv0 & 0xFFFFu);
    float dtv = bf2f(wv0 >> 16);
    f32x2 B2[4] = {{b0.x,b0.y},{b0.z,b0.w},{b1.x,b1.y},{b1.z,b1.w}};
    f32x2 C2[4] = {{c0.x,c0.y},{c0.z,c0.w},{c1.x,c1.y},{c1.z,c1.w}};
    float du = dtv * uv;
    f32x2 y2 = {0.f, 0.f};
    if (fast) {
      float e1 = __expf(-dtv);
      float e2 = e1 * e1, e4 = e2 * e2, e8 = e4 * e4;
      float st = sh ? e8 * e1 : e1;
      f32x2 dA = {st, st * e1};
      f32x2 e22 = {e2, e2};
      f32x2 du2 = {du, du};
#pragma unroll
      for (int j = 0; j < 4; ++j) {
        h2[j] = dA * h2[j] + du2 * B2[j];
        y2 = y2 + h2[j] * C2[j];
        dA = dA * e22;
      }
    } else {
#pragma unroll
      for (int j = 0; j < 8; ++j) {
        float dA = __expf(dtv * a[j]);
        float hh = fmaf(dA, h2[j >> 1][j & 1], du * B2[j >> 1][j & 1]);
        h2[j >> 1][j & 1] = hh;
        y2[j & 1] = fmaf(hh, C2[j >> 1][j & 1], y2[j & 1]);
      }
    }
    float y = y2.x + y2.y;
    y += __shfl_xor(y, 32);
    if (sh == 0) {
      float zs = bf2f((unsigned int)zv0);
      smA[ll * 264 + d] = f2bf(fmaf(uv, dskv, y) * zs);   // ya, bf16
    }
    wv0 = wv1; wv1 = wv2; zv0 = zv1; zv1 = zv2;
  }
  // ---------------- epilogue: out_proj -> LN -> fc -> ReLU ----------------
  const int q = l >> 4, col = l & 15;
  ffrag acc[2][4];
  for (int nt2 = 0; nt2 < 2; ++nt2) {
    __syncthreads();           // iter0: ya complete; iterN: prior MFMA reads done
    for (int i = t; i < 64 * 64; i += 512) {
      int row = i >> 6, c4 = i & 63;
      float4 wv = *(const float4*)&W[((nt2 << 6) + row) * 256 + (c4 << 2)];
      uint2 wp = {f2bf2(wv.x, wv.y), f2bf2(wv.z, wv.w)};
      *(uint2*)&smB[row * 264 + (c4 << 2)] = wp;
    }
    __syncthreads();
    if (t < 256) {
#pragma unroll
      for (int nt = 0; nt < 4; ++nt) acc[nt2][nt] = (ffrag){0.f, 0.f, 0.f, 0.f};
#pragma unroll
      for (int s = 0; s < 8; ++s) {
        int k0 = s * 32 + q * 8;
        bfrag af = *(const bfrag*)&smA[((w << 4) + col) * 264 + k0];
#pragma unroll
        for (int nt = 0; nt < 4; ++nt) {
          bfrag bf_ = *(const bfrag*)&smB[((nt << 4) + col) * 264 + k0];
          acc[nt2][nt] = __builtin_amdgcn_mfma_f32_16x16x32_bf16(af, bf_, acc[nt2][nt], 0, 0, 0);
        }
      }
    }
  }
  float mu[4], rs[4];
  if (t < 256) {
#pragma unroll
    for (int i = 0; i < 4; ++i) {
      float s1 = 0.f, s2 = 0.f;
#pragma unroll
      for (int nt2 = 0; nt2 < 2; ++nt2)
#pragma unroll
        for (int nt = 0; nt < 4; ++nt) {
          float v = acc[nt2][nt][i];
          s1 += v; s2 = fmaf(v, v, s2);
        }
      s1 += __shfl_xor(s1, 1); s2 += __shfl_xor(s2, 1);
      s1 += __shfl_xor(s1, 2); s2 += __shfl_xor(s2, 2);
      s1 += __shfl_xor(s1, 4); s2 += __shfl_xor(s2, 4);
      s1 += __shfl_xor(s1, 8); s2 += __shfl_xor(s2, 8);
      mu[i] = s1 * (1.f / DM);
      float var = s2 * (1.f / DM) - mu[i] * mu[i];
      rs[i] = rsqrtf(var + 1e-5f);
    }
  }
  __syncthreads();   // all MFMA LDS reads done before overlaying smA/smB
  if (t < 256) {
#pragma unroll
    for (int nt2 = 0; nt2 < 2; ++nt2)
#pragma unroll
      for (int nt = 0; nt < 4; ++nt) {
        int n = (nt2 << 6) + (nt << 4) + col;
        float g = gamma[n], be = beta[n];
#pragma unroll
        for (int i = 0; i < 4; ++i) {
          int r = (w << 4) + (q << 2) + i;
          smA[r * 136 + n] = f2bf(fmaf((acc[nt2][nt][i] - mu[i]) * rs[i], g, be));
        }
      }
  }
  for (int i = t; i < 128 * 32; i += 512) {
    int row = i >> 5, c4 = i & 31;
    float4 wv = *(const float4*)&fcw[row * 128 + (c4 << 2)];
    uint2 wp = {f2bf2(wv.x, wv.y), f2bf2(wv.z, wv.w)};
    *(uint2*)&smB[row * 136 + (c4 << 2)] = wp;
  }
  __syncthreads();
  if (t < 256) {
    ffrag a2[8] = {{0.f,0.f,0.f,0.f},{0.f,0.f,0.f,0.f},{0.f,0.f,0.f,0.f},{0.f,0.f,0.f,0.f},
                   {0.f,0.f,0.f,0.f},{0.f,0.f,0.f,0.f},{0.f,0.f,0.f,0.f},{0.f,0.f,0.f,0.f}};
#pragma unroll
    for (int s = 0; s < 4; ++s) {
      int k0 = s * 32 + q * 8;
      bfrag af = *(const bfrag*)&smA[((w << 4) + col) * 136 + k0];
#pragma unroll
      for (int nt = 0; nt < 8; ++nt) {
        bfrag bf_ = *(const bfrag*)&smB[((nt << 4) + col) * 136 + k0];
        a2[nt] = __builtin_amdgcn_mfma_f32_16x16x32_bf16(af, bf_, a2[nt], 0, 0, 0);
      }
    }
#pragma unroll
    for (int nt = 0; nt < 8; ++nt)
#pragma unroll
      for (int i = 0; i < 4; ++i) {
        int ml = (w << 4) + (q << 2) + i;
        out[(base + ml) * 128 + (nt << 4) + col] = fmaxf(a2[nt][i], 0.f);
      }
  }
}

extern "C" void kernel_launch(void* const* d_in, const int* in_sizes, int n_in,
                              void* d_out, int out_size, void* d_ws, size_t ws_size,
                              hipStream_t stream) {
  (void)in_sizes; (void)n_in; (void)out_size; (void)ws_size;
  const float* s    = (const float*)d_in[0];
  const float* w_in = (const float*)d_in[1];
  const float* cw   = (const float*)d_in[2];
  const float* cb   = (const float*)d_in[3];
  const float* xw   = (const float*)d_in[4];
  const float* dtw  = (const float*)d_in[5];
  const float* dtpb = (const float*)d_in[6];
  const float* alog = (const float*)d_in[7];
  const float* dsk  = (const float*)d_in[8];
  const float* ow   = (const float*)d_in[9];
  const float* gam  = (const float*)d_in[10];
  const float* bet  = (const float*)d_in[11];
  const float* fcw  = (const float*)d_in[12];
  float* out = (float*)d_out;
  float* ws  = (float*)d_ws;

  // float-unit offsets; all regions disjoint (audited):
  unsigned short* xb   = (unsigned short*)ws;                 // [0, 4194304)
  unsigned short* zsb  = (unsigned short*)(ws + 4194304);     // [4194304, 8388608)
  unsigned int*   udt  = (unsigned int*)(ws + 8388608);       // [8388608, 16777216)
  float*          Bb   = ws + 16777216;                       // [16777216, 17301504)
  float*          Cb   = ws + 17301504;                       // [17301504, 17825792)
  unsigned short* cP   = (unsigned short*)(ws + 17825792);    // [17825792, 19922944)
  unsigned short* cHe  = (unsigned short*)(ws + 19922944);    // [19922944, 22020096)

  // 1. in_proj (bf16 MFMA, half-split + W pipeline): x -> xb, z -> silu -> zsb
  gemm_bf16_in<<<dim3(2, 512), 256, 0, stream>>>(s, w_in, xb, zsb);
  // 2. fused conv/silu + x_proj (MFMA) + dt_proj (fast softplus); emits udt
  xproj_dtproj<<<512, 512, 0, stream>>>(xb, xw, dtw, dtpb, cw, cb, Bb, Cb, udt);
  // 3-4. chunked selective scan (CH=32, bf16 intermediates)
  scan_phase1<<<B_ * NC, 512, 0, stream>>>(udt, Bb, alog, cP, cHe);
  scan_combine<<<512, 512, 0, stream>>>(cP, cHe);
  // 5. FUSED scan phase 3 (2 chunks/block) + out_proj + LN + fc + ReLU
  scan3_out_ln_fc<<<B_ * NC / 2, 512, 0, stream>>>(udt, Bb, Cb, alog, cP, dsk, zsb,
                                                   ow, gam, bet, fcw, out);
}

// Round 3
// 178.544 us; speedup vs baseline: 1.1730x; 1.0417x over previous
//
#include <hip/hip_runtime.h>
#include <math.h>

#define B_ 8
#define L_ 4096
#define DM 128
#define DI 256
#define DSN 16
#define RK 8
#define M_ (B_*L_)      // 32768 positions
#define NC 128          // number of scan chunks
#define CH 32           // chunk length (NC*CH == L_)
#define CH2 64          // fused phase3 tile: 2 chunks

typedef __attribute__((ext_vector_type(8))) short bfrag;   // 8 bf16 (4 VGPRs)
typedef __attribute__((ext_vector_type(4))) float ffrag;   // 4 fp32 acc
typedef __attribute__((ext_vector_type(2))) float f32x2;   // packed-math pair

// fast silu: v_exp + v_rcp (hardware approx, ~22-bit — far above bf16 needs)
__device__ __forceinline__ float silu_f(float x) {
  return x * __builtin_amdgcn_rcpf(1.f + __expf(-x));
}
// fast softplus: v_exp + v_log instead of libm log1pf
__device__ __forceinline__ float softplus_f(float x) {
  return (x > 20.f) ? x : __logf(1.f + __expf(x));
}

__device__ __forceinline__ unsigned short f2bf(float f) {
  unsigned int u = __builtin_bit_cast(unsigned int, f);
  unsigned int r = (u + 0x7FFFu + ((u >> 16) & 1u)) >> 16;   // RNE
  return (unsigned short)r;
}
__device__ __forceinline__ unsigned int f2bf2(float lo, float hi) {
  return (unsigned int)f2bf(lo) | ((unsigned int)f2bf(hi) << 16);
}
__device__ __forceinline__ float bf2f(unsigned int us) {
  return __builtin_bit_cast(float, us << 16);
}

// ---------------------------------------------------------------------------
// in_proj bf16 MFMA GEMM, half-split + reg-prefetch W pipeline + LDS-staged
// vectorized output. Grid (2, 512): blockIdx.x = output half (0: xb, 1: zsb
// with fused silu).
// ---------------------------------------------------------------------------
__global__ __launch_bounds__(256)
void gemm_bf16_in(const float* __restrict__ A, const float* __restrict__ W,
                  unsigned short* __restrict__ xb, unsigned short* __restrict__ zsb) {
  __shared__ unsigned short As[64 * 136];   // 17.4 KB
  __shared__ unsigned short Ws[64 * 136];   // 17.4 KB
  __shared__ unsigned short Os[64 * 72];    // 9.2 KB
  const int t = threadIdx.x;
  const int m0 = blockIdx.y << 6;
  const int half = blockIdx.x;              // 0 -> xb, 1 -> zsb (silu)
  unsigned short* __restrict__ outp = half ? zsb : xb;
  const float* __restrict__ Wbase = W + (half << 8) * 128;
  for (int i = t; i < 64 * 32; i += 256) {
    int row = i >> 5, c4 = i & 31;
    float4 av = *(const float4*)&A[(m0 + row) * 128 + (c4 << 2)];
    uint2 ap = {f2bf2(av.x, av.y), f2bf2(av.z, av.w)};
    *(uint2*)&As[row * 136 + (c4 << 2)] = ap;
  }
  float4 wr[8];
#pragma unroll
  for (int k = 0; k < 8; ++k) {
    int i = t + (k << 8);
    int row = i >> 5, c4 = i & 31;
    wr[k] = *(const float4*)&Wbase[row * 128 + (c4 << 2)];
  }
#pragma unroll
  for (int k = 0; k < 8; ++k) {
    int i = t + (k << 8);
    int row = i >> 5, c4 = i & 31;
    uint2 wp = {f2bf2(wr[k].x, wr[k].y), f2bf2(wr[k].z, wr[k].w)};
    *(uint2*)&Ws[row * 136 + (c4 << 2)] = wp;
  }
  __syncthreads();
  const int w = t >> 6, l = t & 63, q = l >> 4, col = l & 15;
  for (int jt = 0; jt < 4; ++jt) {
    if (jt < 3) {
#pragma unroll
      for (int k = 0; k < 8; ++k) {
        int i = t + (k << 8);
        int row = i >> 5, c4 = i & 31;
        wr[k] = *(const float4*)&Wbase[(((jt + 1) << 6) + row) * 128 + (c4 << 2)];
      }
    }
    ffrag acc[4] = {{0.f,0.f,0.f,0.f},{0.f,0.f,0.f,0.f},{0.f,0.f,0.f,0.f},{0.f,0.f,0.f,0.f}};
#pragma unroll
    for (int s = 0; s < 4; ++s) {
      int k0 = s * 32 + q * 8;
      bfrag af = *(const bfrag*)&As[((w << 4) + col) * 136 + k0];
#pragma unroll
      for (int nt = 0; nt < 4; ++nt) {
        bfrag bf_ = *(const bfrag*)&Ws[((nt << 4) + col) * 136 + k0];
        acc[nt] = __builtin_amdgcn_mfma_f32_16x16x32_bf16(af, bf_, acc[nt], 0, 0, 0);
      }
    }
    __syncthreads();
#pragma unroll
    for (int nt = 0; nt < 4; ++nt)
#pragma unroll
      for (int i = 0; i < 4; ++i) {
        int ml = (w << 4) + (q << 2) + i;
        float v = acc[nt][i];
        if (half) v = silu_f(v);
        Os[ml * 72 + (nt << 4) + col] = f2bf(v);
      }
    if (jt < 3) {
#pragma unroll
      for (int k = 0; k < 8; ++k) {
        int i = t + (k << 8);
        int row = i >> 5, c4 = i & 31;
        uint2 wp = {f2bf2(wr[k].x, wr[k].y), f2bf2(wr[k].z, wr[k].w)};
        *(uint2*)&Ws[row * 136 + (c4 << 2)] = wp;
      }
    }
    __syncthreads();
    {
      int r = t >> 2, c8 = (t & 3) << 3;
      int m = m0 + r;
      *(uint4*)&outp[m * 256 + (jt << 6) + c8]      = *(const uint4*)&Os[r * 72 + c8];
      *(uint4*)&outp[m * 256 + (jt << 6) + 32 + c8] = *(const uint4*)&Os[r * 72 + 32 + c8];
    }
  }
}

// ---------------------------------------------------------------------------
// Fused conv(4)+SiLU -> bf16 LDS -> MFMA x_proj -> dt_proj + softplus.
// ---------------------------------------------------------------------------
__global__ __launch_bounds__(512)
void xproj_dtproj(const unsigned short* __restrict__ xb, const float* __restrict__ xw,
                  const float* __restrict__ dtw, const float* __restrict__ dtpb,
                  const float* __restrict__ cw, const float* __restrict__ cb,
                  float* __restrict__ Bb, float* __restrict__ Cb,
                  unsigned int* __restrict__ udt) {
  __shared__ unsigned short ua[64 * 264];   // u bf16
  __shared__ unsigned short wb[48 * 264];   // xw bf16; rows 40..47 zeroed
  __shared__ float dtr_s[64 * 12];
  const int t = threadIdx.x;
  const int p0 = blockIdx.x << 6;
  {
    const int k = t & 255, half = t >> 8;
    const int pstart = half << 5;
    const int base = p0 + pstart;
    const int lb = base & (L_ - 1);
    const float w0 = cw[k*4], w1 = cw[k*4+1], w2 = cw[k*4+2], w3 = cw[k*4+3];
    const float bias = cb[k];
    float x0 = (lb >= 3) ? bf2f((unsigned int)xb[(base - 3) * 256 + k]) : 0.f;
    float x1 = (lb >= 2) ? bf2f((unsigned int)xb[(base - 2) * 256 + k]) : 0.f;
    float x2 = (lb >= 1) ? bf2f((unsigned int)xb[(base - 1) * 256 + k]) : 0.f;
#pragma unroll 8
    for (int it = 0; it < 32; ++it) {
      float x3 = bf2f((unsigned int)xb[(base + it) * 256 + k]);
      float u = silu_f(fmaf(w0, x0, fmaf(w1, x1, fmaf(w2, x2, fmaf(w3, x3, bias)))));
      ua[(pstart + it) * 264 + k] = f2bf(u);
      x0 = x1; x1 = x2; x2 = x3;
    }
  }
  for (int i = t; i < 40 * 256; i += 512) {
    int n = i >> 8, k = i & 255;
    wb[n * 264 + k] = f2bf(xw[i]);
  }
  for (int i = t; i < 8 * 264; i += 512) wb[40 * 264 + i] = 0;
  __syncthreads();
  const int w = t >> 6, l = t & 63, q = l >> 4, col = l & 15;
  for (int tile = w; tile < 12; tile += 8) {
    const int mt = tile & 3, nt = tile >> 2;
    ffrag acc = {0.f, 0.f, 0.f, 0.f};
#pragma unroll
    for (int s = 0; s < 8; ++s) {
      int k0 = s * 32 + q * 8;
      bfrag af = *(const bfrag*)&ua[((mt << 4) + col) * 264 + k0];
      bfrag bf_ = *(const bfrag*)&wb[((nt << 4) + col) * 264 + k0];
      acc = __builtin_amdgcn_mfma_f32_16x16x32_bf16(af, bf_, acc, 0, 0, 0);
    }
#pragma unroll
    for (int i = 0; i < 4; ++i) {
      int ml = (mt << 4) + (q << 2) + i;
      int m = p0 + ml;
      if (nt == 0) {
        if (col < 8) dtr_s[ml * 12 + col] = acc[i];
        else         Bb[m * 16 + (col - 8)] = acc[i];
      } else if (nt == 1) {
        if (col < 8) Bb[m * 16 + 8 + col] = acc[i];
        else         Cb[m * 16 + (col - 8)] = acc[i];
      } else {
        if (col < 8) Cb[m * 16 + 8 + col] = acc[i];
      }
    }
  }
  __syncthreads();
  {
    const int d = t & 255, half = t >> 8;
    const int pstart = half << 5;
    float w8[8];
    *(float4*)&w8[0] = *(const float4*)&dtw[d * 8];
    *(float4*)&w8[4] = *(const float4*)&dtw[d * 8 + 4];
    const float bias = dtpb[d];
#pragma unroll 4
    for (int pp = pstart; pp < pstart + 32; ++pp) {
      float r0[8];
      *(float4*)&r0[0] = *(const float4*)&dtr_s[pp * 12];
      *(float4*)&r0[4] = *(const float4*)&dtr_s[pp * 12 + 4];
      float a2 = bias;
#pragma unroll
      for (int r2 = 0; r2 < 8; ++r2) a2 = fmaf(r0[r2], w8[r2], a2);
      float sp = softplus_f(a2);
      udt[(p0 + pp) * 256 + d] =
          (unsigned int)ua[pp * 264 + d] | ((unsigned int)f2bf(sp) << 16);
    }
  }
}

// ---------------------------------------------------------------------------
// Scan phase 1 (CH=32): B staged to LDS; udt prefetch depth 2; cP/cHe bf16.
// launch_bounds (512,8): small LDS + ~50 VGPR -> 4 blocks/CU for latency
// hiding on the serial loop.
// ---------------------------------------------------------------------------
__global__ __launch_bounds__(512, 8)
void scan_phase1(const unsigned int* __restrict__ udt,
                 const float* __restrict__ Bb, const float* __restrict__ alog,
                 unsigned short* __restrict__ cP, unsigned short* __restrict__ cHe) {
  __shared__ float Bs[CH * 16];   // 2 KB
  const int bc = blockIdx.x;
  const int b = bc >> 7, c = bc & (NC - 1);
  const int t = threadIdx.x;
  const int l = t & 63, w = t >> 6;
  const int d = (w << 5) + (l & 31);
  const int sh = l >> 5;
  const int soff = sh << 3;
  const int base = b * L_ + c * CH;
  if (t < CH * 4) ((float4*)Bs)[t] = *(const float4*)&Bb[base * 16 + (t << 2)];
  float a[8];
  bool okl = true;
#pragma unroll
  for (int j = 0; j < 8; ++j) {
    a[j] = -__expf(alog[d * 16 + soff + j]);
    float tgt = (float)(soff + j + 1);
    okl = okl && (fabsf(a[j] + tgt) <= 1e-3f * tgt);
  }
  const bool fast = (bool)__all((int)okl);
  f32x2 h2[4] = {{0.f,0.f},{0.f,0.f},{0.f,0.f},{0.f,0.f}};
  float sdt = 0.f;
  unsigned int wv0 = udt[base * 256 + d];
  unsigned int wv1 = udt[(base + 1) * 256 + d];
  __syncthreads();
#pragma unroll 4
  for (int ll = 0; ll < CH; ++ll) {
    const int m2 = base + ((ll + 2 < CH) ? ll + 2 : CH - 1);
    unsigned int wv2 = udt[m2 * 256 + d];
    float4 b0 = *(const float4*)&Bs[ll * 16 + soff];
    float4 b1 = *(const float4*)&Bs[ll * 16 + soff + 4];
    float uv  = bf2f(wv0 & 0xFFFFu);
    float dtv = bf2f(wv0 >> 16);
    f32x2 B2[4] = {{b0.x,b0.y},{b0.z,b0.w},{b1.x,b1.y},{b1.z,b1.w}};
    float du = dtv * uv;
    sdt += dtv;
    if (fast) {
      float e1 = __expf(-dtv);
      float e2 = e1 * e1, e4 = e2 * e2, e8 = e4 * e4;
      float st = sh ? e8 * e1 : e1;
      f32x2 dA = {st, st * e1};
      f32x2 e22 = {e2, e2};
      f32x2 du2 = {du, du};
#pragma unroll
      for (int j = 0; j < 4; ++j) {
        h2[j] = dA * h2[j] + du2 * B2[j];
        dA = dA * e22;
      }
    } else {
#pragma unroll
      for (int j = 0; j < 8; ++j) {
        float dA = __expf(dtv * a[j]);
        h2[j >> 1][j & 1] = fmaf(dA, h2[j >> 1][j & 1], du * B2[j >> 1][j & 1]);
      }
    }
    wv0 = wv1; wv1 = wv2;
  }
#pragma unroll
  for (int j = 0; j < 8; ++j) {
    int o = (bc * 16 + soff + j) * 256 + d;
    cP[o]  = f2bf(__expf(a[j] * sdt));
    cHe[o] = f2bf(h2[j >> 1][j & 1]);
  }
}

// ---------------------------------------------------------------------------
// Hierarchical combine (NC=128, bf16): 512 thr = 64 sd x 8 segments of 16.
// ---------------------------------------------------------------------------
__global__ __launch_bounds__(512)
void scan_combine(unsigned short* __restrict__ cP, const unsigned short* __restrict__ cHe) {
  __shared__ float segP[64 * 9], segH[64 * 9], segS[64 * 9];
  const int t = threadIdx.x;
  const int sdl = t & 63, seg = t >> 6;
  const int blk = blockIdx.x;
  const int b = blk >> 6, grp = blk & 63;
  const int sd = (grp << 6) + sdl;
  const int base = b * NC * 4096 + sd;
  float Pacc = 1.f, Hacc = 0.f;
#pragma unroll
  for (int i = 0; i < 16; ++i) {
    int idx = base + (seg * 16 + i) * 4096;
    float p = bf2f((unsigned int)cP[idx]);
    float he = bf2f((unsigned int)cHe[idx]);
    Hacc = fmaf(p, Hacc, he);
    Pacc *= p;
  }
  segP[sdl * 9 + seg] = Pacc;
  segH[sdl * 9 + seg] = Hacc;
  __syncthreads();
  if (t < 64) {
    float hs = 0.f;
#pragma unroll
    for (int s2 = 0; s2 < 8; ++s2) {
      segS[t * 9 + s2] = hs;
      hs = fmaf(segP[t * 9 + s2], hs, segH[t * 9 + s2]);
    }
  }
  __syncthreads();
  float hs = segS[sdl * 9 + seg];
#pragma unroll
  for (int i = 0; i < 16; ++i) {
    int idx = base + (seg * 16 + i) * 4096;
    float p = bf2f((unsigned int)cP[idx]);
    float he = bf2f((unsigned int)cHe[idx]);
    cP[idx] = f2bf(hs);
    hs = fmaf(p, hs, he);
  }
}

// ---------------------------------------------------------------------------
// FUSED scan phase 3 + out_proj + LayerNorm + fc + ReLU.
// Block = 64 positions = 2 chunks scanned IN PARALLEL (thread t: chunk-half
// t>>8, channel d = t&255, all 16 states per lane). 32 serial iterations,
// no cross-lane shuffle (y reduced in-register), B/C LDS reads are
// wave-uniform broadcasts. Gated y -> smA (64x264 bf16), then the
// out_proj->LN->fc->ReLU epilogue runs in-kernel (waves 0-3).
// LDS: Bs 4K + Cs 4K + ya 33.8K + smB 34.8K = 76.6 KB -> 2 blocks/CU.
// ---------------------------------------------------------------------------
__global__ __launch_bounds__(512, 4)
void scan3_out_ln_fc(const unsigned int* __restrict__ udt,
                     const float* __restrict__ Bb, const float* __restrict__ Cb,
                     const float* __restrict__ alog, const unsigned short* __restrict__ hst,
                     const float* __restrict__ dsk,
                     const unsigned short* __restrict__ zsb,
                     const float* __restrict__ W,
                     const float* __restrict__ gamma, const float* __restrict__ beta,
                     const float* __restrict__ fcw, float* __restrict__ out) {
  __shared__ float Bs[CH2 * 16];             // 4 KB
  __shared__ float Cs[CH2 * 16];             // 4 KB
  __shared__ unsigned short smA[64 * 264];   // ya (stride 264); later hnb (stride 136)
  __shared__ unsigned short smB[128 * 136];  // ow halves (stride 264); later fcw (136)
  const int bc = blockIdx.x;
  const int b = bc >> 6, cc = bc & 63;
  const int t = threadIdx.x;
  const int l = t & 63, w = t >> 6;
  const int chh = t >> 8;                     // which of the 2 parallel chunks
  const int d = t & 255;                      // channel
  const int base = b * L_ + (cc << 1) * CH;   // 64-position tile start
  const int cbase = base + chh * CH;          // this chunk's start
  const int hc = b * NC + (cc << 1) + chh;    // h_start chunk index
  // stage B (threads 0-255) and C (threads 256-511): 64x16 floats each
  if (t < CH2 * 4)           ((float4*)Bs)[t]            = *(const float4*)&Bb[base * 16 + (t << 2)];
  else if (t < CH2 * 8)      ((float4*)Cs)[t - CH2 * 4]  = *(const float4*)&Cb[base * 16 + ((t - CH2 * 4) << 2)];
  // fast-path check: a_s == -(s+1) for all 16 states of this channel
  float a[16];
  bool okl = true;
#pragma unroll
  for (int j = 0; j < 16; ++j) {
    a[j] = -__expf(alog[d * 16 + j]);
    float tgt = (float)(j + 1);
    okl = okl && (fabsf(a[j] + tgt) <= 1e-3f * tgt);
  }
  const bool fast = (bool)__all((int)okl);
  const float dskv = dsk[d];
  f32x2 h2[8];
#pragma unroll
  for (int jj = 0; jj < 8; ++jj) {
    h2[jj][0] = bf2f((unsigned int)hst[(hc * 16 + (jj << 1)) * 256 + d]);
    h2[jj][1] = bf2f((unsigned int)hst[(hc * 16 + (jj << 1) + 1) * 256 + d]);
  }
  unsigned int wv0 = udt[cbase * 256 + d];
  unsigned int wv1 = udt[(cbase + 1) * 256 + d];
  unsigned short zv0 = zsb[cbase * 256 + d];
  unsigned short zv1 = zsb[(cbase + 1) * 256 + d];
  __syncthreads();
#pragma unroll 2
  for (int ll = 0; ll < CH; ++ll) {
    const int l2 = (ll + 2 < CH) ? ll + 2 : CH - 1;
    unsigned int wv2 = udt[(cbase + l2) * 256 + d];
    unsigned short zv2 = zsb[(cbase + l2) * 256 + d];
    const float* brow = &Bs[(chh * CH + ll) * 16];
    const float* crow = &Cs[(chh * CH + ll) * 16];
    float4 b0 = *(const float4*)&brow[0];
    float4 b1 = *(const float4*)&brow[4];
    float4 b2 = *(const float4*)&brow[8];
    float4 b3 = *(const float4*)&brow[12];
    float4 c0 = *(const float4*)&crow[0];
    float4 c1 = *(const float4*)&crow[4];
    float4 c2 = *(const float4*)&crow[8];
    float4 c3 = *(const float4*)&crow[12];
    float uv  = bf2f(wv0 & 0xFFFFu);
    float dtv = bf2f(wv0 >> 16);
    f32x2 B2[8] = {{b0.x,b0.y},{b0.z,b0.w},{b1.x,b1.y},{b1.z,b1.w},
                   {b2.x,b2.y},{b2.z,b2.w},{b3.x,b3.y},{b3.z,b3.w}};
    f32x2 C2[8] = {{c0.x,c0.y},{c0.z,c0.w},{c1.x,c1.y},{c1.z,c1.w},
                   {c2.x,c2.y},{c2.z,c2.w},{c3.x,c3.y},{c3.z,c3.w}};
    float du = dtv * uv;
    f32x2 du2 = {du, du};
    f32x2 y2 = {0.f, 0.f};
    if (fast) {
      float e1 = __expf(-dtv);
      float e2 = e1 * e1;
      f32x2 dA = {e1, e2};        // decay for states 0,1 = e1^1, e1^2
      f32x2 e22 = {e2, e2};
#pragma unroll
      for (int jj = 0; jj < 8; ++jj) {
        h2[jj] = dA * h2[jj] + du2 * B2[jj];
        y2 = y2 + h2[jj] * C2[jj];
        dA = dA * e22;
      }
    } else {
#pragma unroll
      for (int j = 0; j < 16; ++j) {
        float dA = __expf(dtv * a[j]);
        float hh = fmaf(dA, h2[j >> 1][j & 1], du * B2[j >> 1][j & 1]);
        h2[j >> 1][j & 1] = hh;
        y2[j & 1] = fmaf(hh, C2[j >> 1][j & 1], y2[j & 1]);
      }
    }
    float y = y2.x + y2.y;
    float zs = bf2f((unsigned int)zv0);
    smA[(chh * CH + ll) * 264 + d] = f2bf(fmaf(uv, dskv, y) * zs);   // ya, bf16
    wv0 = wv1; wv1 = wv2; zv0 = zv1; zv1 = zv2;
  }
  // ---------------- epilogue: out_proj -> LN -> fc -> ReLU ----------------
  const int q = l >> 4, col = l & 15;
  ffrag acc[2][4];
  for (int nt2 = 0; nt2 < 2; ++nt2) {
    __syncthreads();           // iter0: ya complete; iterN: prior MFMA reads done
    for (int i = t; i < 64 * 64; i += 512) {
      int row = i >> 6, c4 = i & 63;
      float4 wv = *(const float4*)&W[((nt2 << 6) + row) * 256 + (c4 << 2)];
      uint2 wp = {f2bf2(wv.x, wv.y), f2bf2(wv.z, wv.w)};
      *(uint2*)&smB[row * 264 + (c4 << 2)] = wp;
    }
    __syncthreads();
    if (t < 256) {
#pragma unroll
      for (int nt = 0; nt < 4; ++nt) acc[nt2][nt] = (ffrag){0.f, 0.f, 0.f, 0.f};
#pragma unroll
      for (int s = 0; s < 8; ++s) {
        int k0 = s * 32 + q * 8;
        bfrag af = *(const bfrag*)&smA[((w << 4) + col) * 264 + k0];
#pragma unroll
        for (int nt = 0; nt < 4; ++nt) {
          bfrag bf_ = *(const bfrag*)&smB[((nt << 4) + col) * 264 + k0];
          acc[nt2][nt] = __builtin_amdgcn_mfma_f32_16x16x32_bf16(af, bf_, acc[nt2][nt], 0, 0, 0);
        }
      }
    }
  }
  float mu[4], rs[4];
  if (t < 256) {
#pragma unroll
    for (int i = 0; i < 4; ++i) {
      float s1 = 0.f, s2 = 0.f;
#pragma unroll
      for (int nt2 = 0; nt2 < 2; ++nt2)
#pragma unroll
        for (int nt = 0; nt < 4; ++nt) {
          float v = acc[nt2][nt][i];
          s1 += v; s2 = fmaf(v, v, s2);
        }
      s1 += __shfl_xor(s1, 1); s2 += __shfl_xor(s2, 1);
      s1 += __shfl_xor(s1, 2); s2 += __shfl_xor(s2, 2);
      s1 += __shfl_xor(s1, 4); s2 += __shfl_xor(s2, 4);
      s1 += __shfl_xor(s1, 8); s2 += __shfl_xor(s2, 8);
      mu[i] = s1 * (1.f / DM);
      float var = s2 * (1.f / DM) - mu[i] * mu[i];
      rs[i] = rsqrtf(var + 1e-5f);
    }
  }
  __syncthreads();   // all MFMA LDS reads done before overlaying smA/smB
  if (t < 256) {
#pragma unroll
    for (int nt2 = 0; nt2 < 2; ++nt2)
#pragma unroll
      for (int nt = 0; nt < 4; ++nt) {
        int n = (nt2 << 6) + (nt << 4) + col;
        float g = gamma[n], be = beta[n];
#pragma unroll
        for (int i = 0; i < 4; ++i) {
          int r = (w << 4) + (q << 2) + i;
          smA[r * 136 + n] = f2bf(fmaf((acc[nt2][nt][i] - mu[i]) * rs[i], g, be));
        }
      }
  }
  for (int i = t; i < 128 * 32; i += 512) {
    int row = i >> 5, c4 = i & 31;
    float4 wv = *(const float4*)&fcw[row * 128 + (c4 << 2)];
    uint2 wp = {f2bf2(wv.x, wv.y), f2bf2(wv.z, wv.w)};
    *(uint2*)&smB[row * 136 + (c4 << 2)] = wp;
  }
  __syncthreads();
  if (t < 256) {
    ffrag a2[8] = {{0.f,0.f,0.f,0.f},{0.f,0.f,0.f,0.f},{0.f,0.f,0.f,0.f},{0.f,0.f,0.f,0.f},
                   {0.f,0.f,0.f,0.f},{0.f,0.f,0.f,0.f},{0.f,0.f,0.f,0.f},{0.f,0.f,0.f,0.f}};
#pragma unroll
    for (int s = 0; s < 4; ++s) {
      int k0 = s * 32 + q * 8;
      bfrag af = *(const bfrag*)&smA[((w << 4) + col) * 136 + k0];
#pragma unroll
      for (int nt = 0; nt < 8; ++nt) {
        bfrag bf_ = *(const bfrag*)&smB[((nt << 4) + col) * 136 + k0];
        a2[nt] = __builtin_amdgcn_mfma_f32_16x16x32_bf16(af, bf_, a2[nt], 0, 0, 0);
      }
    }
#pragma unroll
    for (int nt = 0; nt < 8; ++nt)
#pragma unroll
      for (int i = 0; i < 4; ++i) {
        int ml = (w << 4) + (q << 2) + i;
        out[(base + ml) * 128 + (nt << 4) + col] = fmaxf(a2[nt][i], 0.f);
      }
  }
}

extern "C" void kernel_launch(void* const* d_in, const int* in_sizes, int n_in,
                              void* d_out, int out_size, void* d_ws, size_t ws_size,
                              hipStream_t stream) {
  (void)in_sizes; (void)n_in; (void)out_size; (void)ws_size;
  const float* s    = (const float*)d_in[0];
  const float* w_in = (const float*)d_in[1];
  const float* cw   = (const float*)d_in[2];
  const float* cb   = (const float*)d_in[3];
  const float* xw   = (const float*)d_in[4];
  const float* dtw  = (const float*)d_in[5];
  const float* dtpb = (const float*)d_in[6];
  const float* alog = (const float*)d_in[7];
  const float* dsk  = (const float*)d_in[8];
  const float* ow   = (const float*)d_in[9];
  const float* gam  = (const float*)d_in[10];
  const float* bet  = (const float*)d_in[11];
  const float* fcw  = (const float*)d_in[12];
  float* out = (float*)d_out;
  float* ws  = (float*)d_ws;

  // float-unit offsets; all regions disjoint (audited):
  unsigned short* xb   = (unsigned short*)ws;                 // [0, 4194304)
  unsigned short* zsb  = (unsigned short*)(ws + 4194304);     // [4194304, 8388608)
  unsigned int*   udt  = (unsigned int*)(ws + 8388608);       // [8388608, 16777216)
  float*          Bb   = ws + 16777216;                       // [16777216, 17301504)
  float*          Cb   = ws + 17301504;                       // [17301504, 17825792)
  unsigned short* cP   = (unsigned short*)(ws + 17825792);    // [17825792, 19922944)
  unsigned short* cHe  = (unsigned short*)(ws + 19922944);    // [19922944, 22020096)

  // 1. in_proj (bf16 MFMA, half-split + W pipeline): x -> xb, z -> silu -> zsb
  gemm_bf16_in<<<dim3(2, 512), 256, 0, stream>>>(s, w_in, xb, zsb);
  // 2. fused conv/silu + x_proj (MFMA) + dt_proj (fast softplus); emits udt
  xproj_dtproj<<<512, 512, 0, stream>>>(xb, xw, dtw, dtpb, cw, cb, Bb, Cb, udt);
  // 3-4. chunked selective scan (CH=32, bf16 intermediates)
  scan_phase1<<<B_ * NC, 512, 0, stream>>>(udt, Bb, alog, cP, cHe);
  scan_combine<<<512, 512, 0, stream>>>(cP, cHe);
  // 5. FUSED scan phase 3 (2 parallel chunks/block) + out_proj + LN + fc + ReLU
  scan3_out_ln_fc<<<B_ * NC / 2, 512, 0, stream>>>(udt, Bb, Cb, alog, cP, dsk, zsb,
                                                   ow, gam, bet, fcw, out);
}

// Round 4
// 172.246 us; speedup vs baseline: 1.2159x; 1.0366x over previous
//
#include <hip/hip_runtime.h>
#include <math.h>

#define B_ 8
#define L_ 4096
#define DM 128
#define DI 256
#define DSN 16
#define RK 8
#define M_ (B_*L_)      // 32768 positions
#define NC 128          // number of scan chunks
#define CH 32           // chunk length (NC*CH == L_)
#define CH2 64          // fused phase3 tile: 2 chunks

typedef __attribute__((ext_vector_type(8))) short bfrag;   // 8 bf16 (4 VGPRs)
typedef __attribute__((ext_vector_type(4))) float ffrag;   // 4 fp32 acc
typedef __attribute__((ext_vector_type(2))) float f32x2;   // packed-math pair

// fast silu: v_exp + v_rcp (hardware approx, ~22-bit — far above bf16 needs)
__device__ __forceinline__ float silu_f(float x) {
  return x * __builtin_amdgcn_rcpf(1.f + __expf(-x));
}
// fast softplus: v_exp + v_log instead of libm log1pf
__device__ __forceinline__ float softplus_f(float x) {
  return (x > 20.f) ? x : __logf(1.f + __expf(x));
}

__device__ __forceinline__ unsigned short f2bf(float f) {
  unsigned int u = __builtin_bit_cast(unsigned int, f);
  unsigned int r = (u + 0x7FFFu + ((u >> 16) & 1u)) >> 16;   // RNE
  return (unsigned short)r;
}
__device__ __forceinline__ unsigned int f2bf2(float lo, float hi) {
  return (unsigned int)f2bf(lo) | ((unsigned int)f2bf(hi) << 16);
}
__device__ __forceinline__ float bf2f(unsigned int us) {
  return __builtin_bit_cast(float, us << 16);
}

// ---------------------------------------------------------------------------
// in_proj bf16 MFMA GEMM, half-split + reg-prefetch W pipeline + LDS-staged
// vectorized output. Grid (2, 512): blockIdx.x = output half (0: xb, 1: zsb
// with fused silu).
// ---------------------------------------------------------------------------
__global__ __launch_bounds__(256)
void gemm_bf16_in(const float* __restrict__ A, const float* __restrict__ W,
                  unsigned short* __restrict__ xb, unsigned short* __restrict__ zsb) {
  __shared__ unsigned short As[64 * 136];   // 17.4 KB
  __shared__ unsigned short Ws[64 * 136];   // 17.4 KB
  __shared__ unsigned short Os[64 * 72];    // 9.2 KB
  const int t = threadIdx.x;
  const int m0 = blockIdx.y << 6;
  const int half = blockIdx.x;              // 0 -> xb, 1 -> zsb (silu)
  unsigned short* __restrict__ outp = half ? zsb : xb;
  const float* __restrict__ Wbase = W + (half << 8) * 128;
  for (int i = t; i < 64 * 32; i += 256) {
    int row = i >> 5, c4 = i & 31;
    float4 av = *(const float4*)&A[(m0 + row) * 128 + (c4 << 2)];
    uint2 ap = {f2bf2(av.x, av.y), f2bf2(av.z, av.w)};
    *(uint2*)&As[row * 136 + (c4 << 2)] = ap;
  }
  float4 wr[8];
#pragma unroll
  for (int k = 0; k < 8; ++k) {
    int i = t + (k << 8);
    int row = i >> 5, c4 = i & 31;
    wr[k] = *(const float4*)&Wbase[row * 128 + (c4 << 2)];
  }
#pragma unroll
  for (int k = 0; k < 8; ++k) {
    int i = t + (k << 8);
    int row = i >> 5, c4 = i & 31;
    uint2 wp = {f2bf2(wr[k].x, wr[k].y), f2bf2(wr[k].z, wr[k].w)};
    *(uint2*)&Ws[row * 136 + (c4 << 2)] = wp;
  }
  __syncthreads();
  const int w = t >> 6, l = t & 63, q = l >> 4, col = l & 15;
  for (int jt = 0; jt < 4; ++jt) {
    if (jt < 3) {
#pragma unroll
      for (int k = 0; k < 8; ++k) {
        int i = t + (k << 8);
        int row = i >> 5, c4 = i & 31;
        wr[k] = *(const float4*)&Wbase[(((jt + 1) << 6) + row) * 128 + (c4 << 2)];
      }
    }
    ffrag acc[4] = {{0.f,0.f,0.f,0.f},{0.f,0.f,0.f,0.f},{0.f,0.f,0.f,0.f},{0.f,0.f,0.f,0.f}};
#pragma unroll
    for (int s = 0; s < 4; ++s) {
      int k0 = s * 32 + q * 8;
      bfrag af = *(const bfrag*)&As[((w << 4) + col) * 136 + k0];
#pragma unroll
      for (int nt = 0; nt < 4; ++nt) {
        bfrag bf_ = *(const bfrag*)&Ws[((nt << 4) + col) * 136 + k0];
        acc[nt] = __builtin_amdgcn_mfma_f32_16x16x32_bf16(af, bf_, acc[nt], 0, 0, 0);
      }
    }
    __syncthreads();
#pragma unroll
    for (int nt = 0; nt < 4; ++nt)
#pragma unroll
      for (int i = 0; i < 4; ++i) {
        int ml = (w << 4) + (q << 2) + i;
        float v = acc[nt][i];
        if (half) v = silu_f(v);
        Os[ml * 72 + (nt << 4) + col] = f2bf(v);
      }
    if (jt < 3) {
#pragma unroll
      for (int k = 0; k < 8; ++k) {
        int i = t + (k << 8);
        int row = i >> 5, c4 = i & 31;
        uint2 wp = {f2bf2(wr[k].x, wr[k].y), f2bf2(wr[k].z, wr[k].w)};
        *(uint2*)&Ws[row * 136 + (c4 << 2)] = wp;
      }
    }
    __syncthreads();
    {
      int r = t >> 2, c8 = (t & 3) << 3;
      int m = m0 + r;
      *(uint4*)&outp[m * 256 + (jt << 6) + c8]      = *(const uint4*)&Os[r * 72 + c8];
      *(uint4*)&outp[m * 256 + (jt << 6) + 32 + c8] = *(const uint4*)&Os[r * 72 + 32 + c8];
    }
  }
}

// ---------------------------------------------------------------------------
// Fused conv(4)+SiLU -> bf16 LDS -> MFMA x_proj -> dt_proj + softplus
// + SCAN PHASE 1 inline (thread = (channel d, chunk-half) already walks one
// 32-position chunk serially; run the 16-state recurrence in-register using
// the bf16-rounded dt/u it just produced, B mirrored to LDS during the MFMA
// epilogue). Deletes the scan_phase1 kernel and its 36 MB of re-reads.
// ---------------------------------------------------------------------------
__global__ __launch_bounds__(512)
void xproj_dtproj(const unsigned short* __restrict__ xb, const float* __restrict__ xw,
                  const float* __restrict__ dtw, const float* __restrict__ dtpb,
                  const float* __restrict__ cw, const float* __restrict__ cb,
                  const float* __restrict__ alog,
                  float* __restrict__ Bb, float* __restrict__ Cb,
                  unsigned int* __restrict__ udt,
                  unsigned short* __restrict__ cP, unsigned short* __restrict__ cHe) {
  __shared__ unsigned short ua[64 * 264];   // u bf16 (33.8 KB)
  __shared__ unsigned short wb[48 * 264];   // xw bf16; rows 40..47 zeroed (25.3 KB)
  __shared__ float dtr_s[64 * 12];          // 3 KB
  __shared__ float Bs_l[64 * 16];           // 4 KB (B mirror for inline scan)
  const int t = threadIdx.x;
  const int p0 = blockIdx.x << 6;
  {
    const int k = t & 255, half = t >> 8;
    const int pstart = half << 5;
    const int base = p0 + pstart;
    const int lb = base & (L_ - 1);
    const float w0 = cw[k*4], w1 = cw[k*4+1], w2 = cw[k*4+2], w3 = cw[k*4+3];
    const float bias = cb[k];
    float x0 = (lb >= 3) ? bf2f((unsigned int)xb[(base - 3) * 256 + k]) : 0.f;
    float x1 = (lb >= 2) ? bf2f((unsigned int)xb[(base - 2) * 256 + k]) : 0.f;
    float x2 = (lb >= 1) ? bf2f((unsigned int)xb[(base - 1) * 256 + k]) : 0.f;
#pragma unroll 8
    for (int it = 0; it < 32; ++it) {
      float x3 = bf2f((unsigned int)xb[(base + it) * 256 + k]);
      float u = silu_f(fmaf(w0, x0, fmaf(w1, x1, fmaf(w2, x2, fmaf(w3, x3, bias)))));
      ua[(pstart + it) * 264 + k] = f2bf(u);
      x0 = x1; x1 = x2; x2 = x3;
    }
  }
  for (int i = t; i < 40 * 256; i += 512) {
    int n = i >> 8, k = i & 255;
    wb[n * 264 + k] = f2bf(xw[i]);
  }
  for (int i = t; i < 8 * 264; i += 512) wb[40 * 264 + i] = 0;
  __syncthreads();
  const int w = t >> 6, l = t & 63, q = l >> 4, col = l & 15;
  for (int tile = w; tile < 12; tile += 8) {
    const int mt = tile & 3, nt = tile >> 2;
    ffrag acc = {0.f, 0.f, 0.f, 0.f};
#pragma unroll
    for (int s = 0; s < 8; ++s) {
      int k0 = s * 32 + q * 8;
      bfrag af = *(const bfrag*)&ua[((mt << 4) + col) * 264 + k0];
      bfrag bf_ = *(const bfrag*)&wb[((nt << 4) + col) * 264 + k0];
      acc = __builtin_amdgcn_mfma_f32_16x16x32_bf16(af, bf_, acc, 0, 0, 0);
    }
#pragma unroll
    for (int i = 0; i < 4; ++i) {
      int ml = (mt << 4) + (q << 2) + i;
      int m = p0 + ml;
      if (nt == 0) {
        if (col < 8) dtr_s[ml * 12 + col] = acc[i];
        else {
          Bb[m * 16 + (col - 8)] = acc[i];
          Bs_l[ml * 16 + (col - 8)] = acc[i];
        }
      } else if (nt == 1) {
        if (col < 8) {
          Bb[m * 16 + 8 + col] = acc[i];
          Bs_l[ml * 16 + 8 + col] = acc[i];
        } else {
          Cb[m * 16 + (col - 8)] = acc[i];
        }
      } else {
        if (col < 8) Cb[m * 16 + 8 + col] = acc[i];
      }
    }
  }
  __syncthreads();
  {
    const int d = t & 255, half = t >> 8;
    const int pstart = half << 5;
    const int gpos = p0 + pstart;             // this thread's chunk start (global)
    const int bb = gpos >> 12;                // batch
    const int cc = (gpos & (L_ - 1)) >> 5;    // chunk within batch
    const int bc = bb * NC + cc;
    float w8[8];
    *(float4*)&w8[0] = *(const float4*)&dtw[d * 8];
    *(float4*)&w8[4] = *(const float4*)&dtw[d * 8 + 4];
    const float bias = dtpb[d];
    // inline scan phase-1 state
    float a[16];
    bool okl = true;
#pragma unroll
    for (int j = 0; j < 16; ++j) {
      a[j] = -__expf(alog[d * 16 + j]);
      float tgt = (float)(j + 1);
      okl = okl && (fabsf(a[j] + tgt) <= 1e-3f * tgt);
    }
    const bool fast = (bool)__all((int)okl);
    f32x2 h2[8] = {{0.f,0.f},{0.f,0.f},{0.f,0.f},{0.f,0.f},
                   {0.f,0.f},{0.f,0.f},{0.f,0.f},{0.f,0.f}};
    float sdt = 0.f;
#pragma unroll 2
    for (int pp = pstart; pp < pstart + 32; ++pp) {
      float r0[8];
      *(float4*)&r0[0] = *(const float4*)&dtr_s[pp * 12];
      *(float4*)&r0[4] = *(const float4*)&dtr_s[pp * 12 + 4];
      float a2 = bias;
#pragma unroll
      for (int r2 = 0; r2 < 8; ++r2) a2 = fmaf(r0[r2], w8[r2], a2);
      float sp = softplus_f(a2);
      unsigned int uq = (unsigned int)ua[pp * 264 + d];
      unsigned short spb = f2bf(sp);
      udt[(p0 + pp) * 256 + d] = uq | ((unsigned int)spb << 16);
      // recurrence consumes the bf16-rounded dt/u (identical to old phase1)
      float dtv = bf2f((unsigned int)spb);
      float uv  = bf2f(uq);
      float du = dtv * uv;
      sdt += dtv;
      const float* brow = &Bs_l[pp * 16];
      float4 b0 = *(const float4*)&brow[0];
      float4 b1 = *(const float4*)&brow[4];
      float4 b2 = *(const float4*)&brow[8];
      float4 b3 = *(const float4*)&brow[12];
      f32x2 B2[8] = {{b0.x,b0.y},{b0.z,b0.w},{b1.x,b1.y},{b1.z,b1.w},
                     {b2.x,b2.y},{b2.z,b2.w},{b3.x,b3.y},{b3.z,b3.w}};
      f32x2 du2 = {du, du};
      if (fast) {
        float e1 = __expf(-dtv);
        float e2 = e1 * e1;
        f32x2 dA = {e1, e2};
        f32x2 e22 = {e2, e2};
#pragma unroll
        for (int jj = 0; jj < 8; ++jj) {
          h2[jj] = dA * h2[jj] + du2 * B2[jj];
          dA = dA * e22;
        }
      } else {
#pragma unroll
        for (int j = 0; j < 16; ++j) {
          float dA = __expf(dtv * a[j]);
          h2[j >> 1][j & 1] = fmaf(dA, h2[j >> 1][j & 1], du * B2[j >> 1][j & 1]);
        }
      }
    }
#pragma unroll
    for (int j = 0; j < 16; ++j) {
      int o = (bc * 16 + j) * 256 + d;
      cP[o]  = f2bf(__expf(a[j] * sdt));
      cHe[o] = f2bf(h2[j >> 1][j & 1]);
    }
  }
}

// ---------------------------------------------------------------------------
// Hierarchical combine (NC=128, bf16): 512 thr = 64 sd x 8 segments of 16.
// ---------------------------------------------------------------------------
__global__ __launch_bounds__(512)
void scan_combine(unsigned short* __restrict__ cP, const unsigned short* __restrict__ cHe) {
  __shared__ float segP[64 * 9], segH[64 * 9], segS[64 * 9];
  const int t = threadIdx.x;
  const int sdl = t & 63, seg = t >> 6;
  const int blk = blockIdx.x;
  const int b = blk >> 6, grp = blk & 63;
  const int sd = (grp << 6) + sdl;
  const int base = b * NC * 4096 + sd;
  float Pacc = 1.f, Hacc = 0.f;
#pragma unroll
  for (int i = 0; i < 16; ++i) {
    int idx = base + (seg * 16 + i) * 4096;
    float p = bf2f((unsigned int)cP[idx]);
    float he = bf2f((unsigned int)cHe[idx]);
    Hacc = fmaf(p, Hacc, he);
    Pacc *= p;
  }
  segP[sdl * 9 + seg] = Pacc;
  segH[sdl * 9 + seg] = Hacc;
  __syncthreads();
  if (t < 64) {
    float hs = 0.f;
#pragma unroll
    for (int s2 = 0; s2 < 8; ++s2) {
      segS[t * 9 + s2] = hs;
      hs = fmaf(segP[t * 9 + s2], hs, segH[t * 9 + s2]);
    }
  }
  __syncthreads();
  float hs = segS[sdl * 9 + seg];
#pragma unroll
  for (int i = 0; i < 16; ++i) {
    int idx = base + (seg * 16 + i) * 4096;
    float p = bf2f((unsigned int)cP[idx]);
    float he = bf2f((unsigned int)cHe[idx]);
    cP[idx] = f2bf(hs);
    hs = fmaf(p, hs, he);
  }
}

// ---------------------------------------------------------------------------
// FUSED scan phase 3 + out_proj + LayerNorm + fc + ReLU.
// Block = 64 positions = 2 chunks scanned IN PARALLEL (thread t: chunk-half
// t>>8, channel d = t&255, all 16 states per lane). 32 serial iterations,
// no cross-lane shuffle (y reduced in-register), B/C LDS reads are
// wave-uniform broadcasts. Gated y -> smA (64x264 bf16), then the
// out_proj->LN->fc->ReLU epilogue runs in-kernel (waves 0-3).
// LDS: Bs 4K + Cs 4K + ya 33.8K + smB 34.8K = 76.6 KB -> 2 blocks/CU.
// ---------------------------------------------------------------------------
__global__ __launch_bounds__(512, 4)
void scan3_out_ln_fc(const unsigned int* __restrict__ udt,
                     const float* __restrict__ Bb, const float* __restrict__ Cb,
                     const float* __restrict__ alog, const unsigned short* __restrict__ hst,
                     const float* __restrict__ dsk,
                     const unsigned short* __restrict__ zsb,
                     const float* __restrict__ W,
                     const float* __restrict__ gamma, const float* __restrict__ beta,
                     const float* __restrict__ fcw, float* __restrict__ out) {
  __shared__ float Bs[CH2 * 16];             // 4 KB
  __shared__ float Cs[CH2 * 16];             // 4 KB
  __shared__ unsigned short smA[64 * 264];   // ya (stride 264); later hnb (stride 136)
  __shared__ unsigned short smB[128 * 136];  // ow halves (stride 264); later fcw (136)
  const int bc = blockIdx.x;
  const int b = bc >> 6, cc = bc & 63;
  const int t = threadIdx.x;
  const int l = t & 63, w = t >> 6;
  const int chh = t >> 8;                     // which of the 2 parallel chunks
  const int d = t & 255;                      // channel
  const int base = b * L_ + (cc << 1) * CH;   // 64-position tile start
  const int cbase = base + chh * CH;          // this chunk's start
  const int hc = b * NC + (cc << 1) + chh;    // h_start chunk index
  // stage B (threads 0-255) and C (threads 256-511): 64x16 floats each
  if (t < CH2 * 4)           ((float4*)Bs)[t]            = *(const float4*)&Bb[base * 16 + (t << 2)];
  else if (t < CH2 * 8)      ((float4*)Cs)[t - CH2 * 4]  = *(const float4*)&Cb[base * 16 + ((t - CH2 * 4) << 2)];
  // fast-path check: a_s == -(s+1) for all 16 states of this channel
  float a[16];
  bool okl = true;
#pragma unroll
  for (int j = 0; j < 16; ++j) {
    a[j] = -__expf(alog[d * 16 + j]);
    float tgt = (float)(j + 1);
    okl = okl && (fabsf(a[j] + tgt) <= 1e-3f * tgt);
  }
  const bool fast = (bool)__all((int)okl);
  const float dskv = dsk[d];
  f32x2 h2[8];
#pragma unroll
  for (int jj = 0; jj < 8; ++jj) {
    h2[jj][0] = bf2f((unsigned int)hst[(hc * 16 + (jj << 1)) * 256 + d]);
    h2[jj][1] = bf2f((unsigned int)hst[(hc * 16 + (jj << 1) + 1) * 256 + d]);
  }
  unsigned int wv0 = udt[cbase * 256 + d];
  unsigned int wv1 = udt[(cbase + 1) * 256 + d];
  unsigned short zv0 = zsb[cbase * 256 + d];
  unsigned short zv1 = zsb[(cbase + 1) * 256 + d];
  __syncthreads();
#pragma unroll 2
  for (int ll = 0; ll < CH; ++ll) {
    const int l2 = (ll + 2 < CH) ? ll + 2 : CH - 1;
    unsigned int wv2 = udt[(cbase + l2) * 256 + d];
    unsigned short zv2 = zsb[(cbase + l2) * 256 + d];
    const float* brow = &Bs[(chh * CH + ll) * 16];
    const float* crow = &Cs[(chh * CH + ll) * 16];
    float4 b0 = *(const float4*)&brow[0];
    float4 b1 = *(const float4*)&brow[4];
    float4 b2 = *(const float4*)&brow[8];
    float4 b3 = *(const float4*)&brow[12];
    float4 c0 = *(const float4*)&crow[0];
    float4 c1 = *(const float4*)&crow[4];
    float4 c2 = *(const float4*)&crow[8];
    float4 c3 = *(const float4*)&crow[12];
    float uv  = bf2f(wv0 & 0xFFFFu);
    float dtv = bf2f(wv0 >> 16);
    f32x2 B2[8] = {{b0.x,b0.y},{b0.z,b0.w},{b1.x,b1.y},{b1.z,b1.w},
                   {b2.x,b2.y},{b2.z,b2.w},{b3.x,b3.y},{b3.z,b3.w}};
    f32x2 C2[8] = {{c0.x,c0.y},{c0.z,c0.w},{c1.x,c1.y},{c1.z,c1.w},
                   {c2.x,c2.y},{c2.z,c2.w},{c3.x,c3.y},{c3.z,c3.w}};
    float du = dtv * uv;
    f32x2 du2 = {du, du};
    f32x2 y2 = {0.f, 0.f};
    if (fast) {
      float e1 = __expf(-dtv);
      float e2 = e1 * e1;
      f32x2 dA = {e1, e2};        // decay for states 0,1 = e1^1, e1^2
      f32x2 e22 = {e2, e2};
#pragma unroll
      for (int jj = 0; jj < 8; ++jj) {
        h2[jj] = dA * h2[jj] + du2 * B2[jj];
        y2 = y2 + h2[jj] * C2[jj];
        dA = dA * e22;
      }
    } else {
#pragma unroll
      for (int j = 0; j < 16; ++j) {
        float dA = __expf(dtv * a[j]);
        float hh = fmaf(dA, h2[j >> 1][j & 1], du * B2[j >> 1][j & 1]);
        h2[j >> 1][j & 1] = hh;
        y2[j & 1] = fmaf(hh, C2[j >> 1][j & 1], y2[j & 1]);
      }
    }
    float y = y2.x + y2.y;
    float zs = bf2f((unsigned int)zv0);
    smA[(chh * CH + ll) * 264 + d] = f2bf(fmaf(uv, dskv, y) * zs);   // ya, bf16
    wv0 = wv1; wv1 = wv2; zv0 = zv1; zv1 = zv2;
  }
  // ---------------- epilogue: out_proj -> LN -> fc -> ReLU ----------------
  const int q = l >> 4, col = l & 15;
  ffrag acc[2][4];
  for (int nt2 = 0; nt2 < 2; ++nt2) {
    __syncthreads();           // iter0: ya complete; iterN: prior MFMA reads done
    for (int i = t; i < 64 * 64; i += 512) {
      int row = i >> 6, c4 = i & 63;
      float4 wv = *(const float4*)&W[((nt2 << 6) + row) * 256 + (c4 << 2)];
      uint2 wp = {f2bf2(wv.x, wv.y), f2bf2(wv.z, wv.w)};
      *(uint2*)&smB[row * 264 + (c4 << 2)] = wp;
    }
    __syncthreads();
    if (t < 256) {
#pragma unroll
      for (int nt = 0; nt < 4; ++nt) acc[nt2][nt] = (ffrag){0.f, 0.f, 0.f, 0.f};
#pragma unroll
      for (int s = 0; s < 8; ++s) {
        int k0 = s * 32 + q * 8;
        bfrag af = *(const bfrag*)&smA[((w << 4) + col) * 264 + k0];
#pragma unroll
        for (int nt = 0; nt < 4; ++nt) {
          bfrag bf_ = *(const bfrag*)&smB[((nt << 4) + col) * 264 + k0];
          acc[nt2][nt] = __builtin_amdgcn_mfma_f32_16x16x32_bf16(af, bf_, acc[nt2][nt], 0, 0, 0);
        }
      }
    }
  }
  float mu[4], rs[4];
  if (t < 256) {
#pragma unroll
    for (int i = 0; i < 4; ++i) {
      float s1 = 0.f, s2 = 0.f;
#pragma unroll
      for (int nt2 = 0; nt2 < 2; ++nt2)
#pragma unroll
        for (int nt = 0; nt < 4; ++nt) {
          float v = acc[nt2][nt][i];
          s1 += v; s2 = fmaf(v, v, s2);
        }
      s1 += __shfl_xor(s1, 1); s2 += __shfl_xor(s2, 1);
      s1 += __shfl_xor(s1, 2); s2 += __shfl_xor(s2, 2);
      s1 += __shfl_xor(s1, 4); s2 += __shfl_xor(s2, 4);
      s1 += __shfl_xor(s1, 8); s2 += __shfl_xor(s2, 8);
      mu[i] = s1 * (1.f / DM);
      float var = s2 * (1.f / DM) - mu[i] * mu[i];
      rs[i] = rsqrtf(var + 1e-5f);
    }
  }
  __syncthreads();   // all MFMA LDS reads done before overlaying smA/smB
  if (t < 256) {
#pragma unroll
    for (int nt2 = 0; nt2 < 2; ++nt2)
#pragma unroll
      for (int nt = 0; nt < 4; ++nt) {
        int n = (nt2 << 6) + (nt << 4) + col;
        float g = gamma[n], be = beta[n];
#pragma unroll
        for (int i = 0; i < 4; ++i) {
          int r = (w << 4) + (q << 2) + i;
          smA[r * 136 + n] = f2bf(fmaf((acc[nt2][nt][i] - mu[i]) * rs[i], g, be));
        }
      }
  }
  for (int i = t; i < 128 * 32; i += 512) {
    int row = i >> 5, c4 = i & 31;
    float4 wv = *(const float4*)&fcw[row * 128 + (c4 << 2)];
    uint2 wp = {f2bf2(wv.x, wv.y), f2bf2(wv.z, wv.w)};
    *(uint2*)&smB[row * 136 + (c4 << 2)] = wp;
  }
  __syncthreads();
  if (t < 256) {
    ffrag a2[8] = {{0.f,0.f,0.f,0.f},{0.f,0.f,0.f,0.f},{0.f,0.f,0.f,0.f},{0.f,0.f,0.f,0.f},
                   {0.f,0.f,0.f,0.f},{0.f,0.f,0.f,0.f},{0.f,0.f,0.f,0.f},{0.f,0.f,0.f,0.f}};
#pragma unroll
    for (int s = 0; s < 4; ++s) {
      int k0 = s * 32 + q * 8;
      bfrag af = *(const bfrag*)&smA[((w << 4) + col) * 136 + k0];
#pragma unroll
      for (int nt = 0; nt < 8; ++nt) {
        bfrag bf_ = *(const bfrag*)&smB[((nt << 4) + col) * 136 + k0];
        a2[nt] = __builtin_amdgcn_mfma_f32_16x16x32_bf16(af, bf_, a2[nt], 0, 0, 0);
      }
    }
#pragma unroll
    for (int nt = 0; nt < 8; ++nt)
#pragma unroll
      for (int i = 0; i < 4; ++i) {
        int ml = (w << 4) + (q << 2) + i;
        out[(base + ml) * 128 + (nt << 4) + col] = fmaxf(a2[nt][i], 0.f);
      }
  }
}

extern "C" void kernel_launch(void* const* d_in, const int* in_sizes, int n_in,
                              void* d_out, int out_size, void* d_ws, size_t ws_size,
                              hipStream_t stream) {
  (void)in_sizes; (void)n_in; (void)out_size; (void)ws_size;
  const float* s    = (const float*)d_in[0];
  const float* w_in = (const float*)d_in[1];
  const float* cw   = (const float*)d_in[2];
  const float* cb   = (const float*)d_in[3];
  const float* xw   = (const float*)d_in[4];
  const float* dtw  = (const float*)d_in[5];
  const float* dtpb = (const float*)d_in[6];
  const float* alog = (const float*)d_in[7];
  const float* dsk  = (const float*)d_in[8];
  const float* ow   = (const float*)d_in[9];
  const float* gam  = (const float*)d_in[10];
  const float* bet  = (const float*)d_in[11];
  const float* fcw  = (const float*)d_in[12];
  float* out = (float*)d_out;
  float* ws  = (float*)d_ws;

  // float-unit offsets; all regions disjoint (audited):
  unsigned short* xb   = (unsigned short*)ws;                 // [0, 4194304)
  unsigned short* zsb  = (unsigned short*)(ws + 4194304);     // [4194304, 8388608)
  unsigned int*   udt  = (unsigned int*)(ws + 8388608);       // [8388608, 16777216)
  float*          Bb   = ws + 16777216;                       // [16777216, 17301504)
  float*          Cb   = ws + 17301504;                       // [17301504, 17825792)
  unsigned short* cP   = (unsigned short*)(ws + 17825792);    // [17825792, 19922944)
  unsigned short* cHe  = (unsigned short*)(ws + 19922944);    // [19922944, 22020096)

  // 1. in_proj (bf16 MFMA, half-split + W pipeline): x -> xb, z -> silu -> zsb
  gemm_bf16_in<<<dim3(2, 512), 256, 0, stream>>>(s, w_in, xb, zsb);
  // 2. fused conv/silu + x_proj (MFMA) + dt_proj + INLINE scan phase 1
  xproj_dtproj<<<512, 512, 0, stream>>>(xb, xw, dtw, dtpb, cw, cb, alog,
                                        Bb, Cb, udt, cP, cHe);
  // 3. inter-chunk combine
  scan_combine<<<512, 512, 0, stream>>>(cP, cHe);
  // 4. FUSED scan phase 3 (2 parallel chunks/block) + out_proj + LN + fc + ReLU
  scan3_out_ln_fc<<<B_ * NC / 2, 512, 0, stream>>>(udt, Bb, Cb, alog, cP, dsk, zsb,
                                                   ow, gam, bet, fcw, out);
}

// Round 5
// 168.733 us; speedup vs baseline: 1.2412x; 1.0208x over previous
//
#include <hip/hip_runtime.h>
#include <math.h>

#define B_ 8
#define L_ 4096
#define DM 128
#define DI 256
#define DSN 16
#define RK 8
#define M_ (B_*L_)      // 32768 positions
#define NC 128          // number of scan chunks
#define CH 32           // chunk length (NC*CH == L_)
#define CH2 64          // fused phase3 tile: 2 chunks

typedef __attribute__((ext_vector_type(8))) short bfrag;   // 8 bf16 (4 VGPRs)
typedef __attribute__((ext_vector_type(4))) float ffrag;   // 4 fp32 acc
typedef __attribute__((ext_vector_type(2))) float f32x2;   // packed-math pair

// fast silu: v_exp + v_rcp (hardware approx, ~22-bit — far above bf16 needs)
__device__ __forceinline__ float silu_f(float x) {
  return x * __builtin_amdgcn_rcpf(1.f + __expf(-x));
}
// fast softplus: v_exp + v_log instead of libm log1pf
__device__ __forceinline__ float softplus_f(float x) {
  return (x > 20.f) ? x : __logf(1.f + __expf(x));
}

__device__ __forceinline__ unsigned short f2bf(float f) {
  unsigned int u = __builtin_bit_cast(unsigned int, f);
  unsigned int r = (u + 0x7FFFu + ((u >> 16) & 1u)) >> 16;   // RNE
  return (unsigned short)r;
}
__device__ __forceinline__ unsigned int f2bf2(float lo, float hi) {
  return (unsigned int)f2bf(lo) | ((unsigned int)f2bf(hi) << 16);
}
__device__ __forceinline__ float bf2f(unsigned int us) {
  return __builtin_bit_cast(float, us << 16);
}

// ---------------------------------------------------------------------------
// MEGA-FUSED front end: in_proj GEMM (x half -> LDS, z half -> silu -> zsb)
// + conv(4)+SiLU + x_proj MFMA + dt_proj + INLINE scan phase 1.
// One block per 64 positions. The conv's 3-position lookback is satisfied by
// a 16-row halo m-tile (positions p0-16..p0-1; only last 3 used, batch
// boundaries masked by the same lb checks as before -> bit-identical).
// Deletes the gemm_bf16_in kernel and the 33.6 MB xb round-trip.
// LDS pool 74.5 KB with phase overlays:
//   P1 (in_proj):  As 80x136 (21.8K) + Ws 64x136 (17.4K) + hx 67x264 (35.4K)
//   P2 (conv):     ua 64x264 (33.8K, overlays As+Ws) + hx
//   P3 (x_proj):   ua + wb 48x264 (25.3K, overlays hx) + dtr_s 3K + Bs_l 4K
// -> 2 blocks/CU at 512 threads (launch_bounds pins VGPR <= 128).
// ---------------------------------------------------------------------------
__global__ __launch_bounds__(512, 4)
void xproj_dtproj(const float* __restrict__ s, const float* __restrict__ w_in,
                  const float* __restrict__ xw,
                  const float* __restrict__ dtw, const float* __restrict__ dtpb,
                  const float* __restrict__ cw, const float* __restrict__ cb,
                  const float* __restrict__ alog,
                  float* __restrict__ Bb, float* __restrict__ Cb,
                  unsigned int* __restrict__ udt,
                  unsigned short* __restrict__ zsb,
                  unsigned short* __restrict__ cP, unsigned short* __restrict__ cHe) {
  __shared__ __align__(16) char pool[74544];
  unsigned short* As = (unsigned short*)pool;              // 80*136*2 = 21760
  unsigned short* Ws = (unsigned short*)(pool + 21760);    // 64*136*2 = 17408
  unsigned short* ua = (unsigned short*)pool;              // 64*264*2 = 33792 (overlay As+Ws)
  unsigned short* hx = (unsigned short*)(pool + 39168);    // 67*264*2 = 35376
  unsigned short* wb = (unsigned short*)(pool + 39168);    // 48*264*2 = 25344 (overlay hx)
  float* dtr_s = (float*)(pool + 64512);                   // 64*12*4  = 3072
  float* Bs_l  = (float*)(pool + 67584);                   // 64*16*4  = 4096
  const int t = threadIdx.x;
  const int p0 = blockIdx.x << 6;
  const int w = t >> 6, l = t & 63, q = l >> 4, col = l & 15;

  // ---- P1: stage A (64 main rows + 16 halo rows of s, f32 -> bf16) ----
  for (int i = t; i < 80 * 32; i += 512) {
    int row = i >> 5, c4 = i & 31;
    int pos = (row < 64) ? (p0 + row) : (p0 - 16 + (row - 64));
    if (pos < 0) pos = 0;                       // block 0 halo: clamped, masked later
    float4 av = *(const float4*)&s[pos * 128 + (c4 << 2)];
    uint2 ap = {f2bf2(av.x, av.y), f2bf2(av.z, av.w)};
    *(uint2*)&As[row * 136 + (c4 << 2)] = ap;
  }
  // W pass 0 into Ws (reg staged)
  float4 wr[4];
#pragma unroll
  for (int k = 0; k < 4; ++k) {
    int i = t + (k << 9);
    int row = i >> 5, c4 = i & 31;
    wr[k] = *(const float4*)&w_in[row * 128 + (c4 << 2)];
  }
#pragma unroll
  for (int k = 0; k < 4; ++k) {
    int i = t + (k << 9);
    int row = i >> 5, c4 = i & 31;
    uint2 wp = {f2bf2(wr[k].x, wr[k].y), f2bf2(wr[k].z, wr[k].w)};
    *(uint2*)&Ws[row * 136 + (c4 << 2)] = wp;
  }
  __syncthreads();
  // ---- in_proj: 8 passes of 64 W rows (0-3: x half, 4-7: z half) ----
  for (int jt = 0; jt < 8; ++jt) {
    if (jt < 7) {
#pragma unroll
      for (int k = 0; k < 4; ++k) {
        int i = t + (k << 9);
        int row = i >> 5, c4 = i & 31;
        wr[k] = *(const float4*)&w_in[(((jt + 1) << 6) + row) * 128 + (c4 << 2)];
      }
    }
    const int T = (jt < 4) ? 20 : 16;           // x passes include halo m-tile 4
    for (int tile = w; tile < T; tile += 8) {
      const int mt = tile >> 2, nt = tile & 3;
      ffrag acc = {0.f, 0.f, 0.f, 0.f};
#pragma unroll
      for (int s8 = 0; s8 < 4; ++s8) {
        int k0 = s8 * 32 + q * 8;
        bfrag af = *(const bfrag*)&As[((mt << 4) + col) * 136 + k0];
        bfrag bf_ = *(const bfrag*)&Ws[((nt << 4) + col) * 136 + k0];
        acc = __builtin_amdgcn_mfma_f32_16x16x32_bf16(af, bf_, acc, 0, 0, 0);
      }
      if (jt < 4) {
        const int ch = (jt << 6) + (nt << 4) + col;
#pragma unroll
        for (int i = 0; i < 4; ++i) {
          int rt = (q << 2) + i;
          if (mt < 4) {
            hx[(3 + (mt << 4) + rt) * 264 + ch] = f2bf(acc[i]);
          } else {
            int hr = rt - 13;                   // halo rows: positions p0-3..p0-1
            if (hr >= 0) hx[hr * 264 + ch] = f2bf(acc[i]);
          }
        }
      } else {
        const int ch = ((jt - 4) << 6) + (nt << 4) + col;
#pragma unroll
        for (int i = 0; i < 4; ++i) {
          int m = p0 + (mt << 4) + (q << 2) + i;
          zsb[m * 256 + ch] = f2bf(silu_f(acc[i]));
        }
      }
    }
    __syncthreads();
    if (jt < 7) {
#pragma unroll
      for (int k = 0; k < 4; ++k) {
        int i = t + (k << 9);
        int row = i >> 5, c4 = i & 31;
        uint2 wp = {f2bf2(wr[k].x, wr[k].y), f2bf2(wr[k].z, wr[k].w)};
        *(uint2*)&Ws[row * 136 + (c4 << 2)] = wp;
      }
      __syncthreads();
    }
  }
  // ---- P2: conv(4)+SiLU from hx (LDS) -> ua (overlays As/Ws) ----
  {
    const int k = t & 255, half = t >> 8;
    const int pstart = half << 5;
    const int base = p0 + pstart;
    const int lb = base & (L_ - 1);
    const float w0 = cw[k*4], w1 = cw[k*4+1], w2 = cw[k*4+2], w3 = cw[k*4+3];
    const float bias = cb[k];
    float x0 = (lb >= 3) ? bf2f((unsigned int)hx[(pstart + 0) * 264 + k]) : 0.f;
    float x1 = (lb >= 2) ? bf2f((unsigned int)hx[(pstart + 1) * 264 + k]) : 0.f;
    float x2 = (lb >= 1) ? bf2f((unsigned int)hx[(pstart + 2) * 264 + k]) : 0.f;
#pragma unroll 8
    for (int it = 0; it < 32; ++it) {
      float x3 = bf2f((unsigned int)hx[(pstart + 3 + it) * 264 + k]);
      float u = silu_f(fmaf(w0, x0, fmaf(w1, x1, fmaf(w2, x2, fmaf(w3, x3, bias)))));
      ua[(pstart + it) * 264 + k] = f2bf(u);
      x0 = x1; x1 = x2; x2 = x3;
    }
  }
  __syncthreads();
  // ---- P3: stage xw (wb overlays hx) ----
  for (int i = t; i < 40 * 256; i += 512) {
    int n = i >> 8, k = i & 255;
    wb[n * 264 + k] = f2bf(xw[i]);
  }
  for (int i = t; i < 8 * 264; i += 512) wb[40 * 264 + i] = 0;
  __syncthreads();
  // x_proj MFMA (12 tiles over 8 waves)
  for (int tile = w; tile < 12; tile += 8) {
    const int mt = tile & 3, nt = tile >> 2;
    ffrag acc = {0.f, 0.f, 0.f, 0.f};
#pragma unroll
    for (int s8 = 0; s8 < 8; ++s8) {
      int k0 = s8 * 32 + q * 8;
      bfrag af = *(const bfrag*)&ua[((mt << 4) + col) * 264 + k0];
      bfrag bf_ = *(const bfrag*)&wb[((nt << 4) + col) * 264 + k0];
      acc = __builtin_amdgcn_mfma_f32_16x16x32_bf16(af, bf_, acc, 0, 0, 0);
    }
#pragma unroll
    for (int i = 0; i < 4; ++i) {
      int ml = (mt << 4) + (q << 2) + i;
      int m = p0 + ml;
      if (nt == 0) {
        if (col < 8) dtr_s[ml * 12 + col] = acc[i];
        else {
          Bb[m * 16 + (col - 8)] = acc[i];
          Bs_l[ml * 16 + (col - 8)] = acc[i];
        }
      } else if (nt == 1) {
        if (col < 8) {
          Bb[m * 16 + 8 + col] = acc[i];
          Bs_l[ml * 16 + 8 + col] = acc[i];
        } else {
          Cb[m * 16 + (col - 8)] = acc[i];
        }
      } else {
        if (col < 8) Cb[m * 16 + 8 + col] = acc[i];
      }
    }
  }
  __syncthreads();
  // ---- dt_proj + softplus + inline scan phase 1 ----
  {
    const int d = t & 255, half = t >> 8;
    const int pstart = half << 5;
    const int gpos = p0 + pstart;             // this thread's chunk start (global)
    const int bb = gpos >> 12;                // batch
    const int cc = (gpos & (L_ - 1)) >> 5;    // chunk within batch
    const int bc = bb * NC + cc;
    float w8[8];
    *(float4*)&w8[0] = *(const float4*)&dtw[d * 8];
    *(float4*)&w8[4] = *(const float4*)&dtw[d * 8 + 4];
    const float bias = dtpb[d];
    float a[16];
    bool okl = true;
#pragma unroll
    for (int j = 0; j < 16; ++j) {
      a[j] = -__expf(alog[d * 16 + j]);
      float tgt = (float)(j + 1);
      okl = okl && (fabsf(a[j] + tgt) <= 1e-3f * tgt);
    }
    const bool fast = (bool)__all((int)okl);
    f32x2 h2[8] = {{0.f,0.f},{0.f,0.f},{0.f,0.f},{0.f,0.f},
                   {0.f,0.f},{0.f,0.f},{0.f,0.f},{0.f,0.f}};
    float sdt = 0.f;
#pragma unroll 2
    for (int pp = pstart; pp < pstart + 32; ++pp) {
      float r0[8];
      *(float4*)&r0[0] = *(const float4*)&dtr_s[pp * 12];
      *(float4*)&r0[4] = *(const float4*)&dtr_s[pp * 12 + 4];
      float a2 = bias;
#pragma unroll
      for (int r2 = 0; r2 < 8; ++r2) a2 = fmaf(r0[r2], w8[r2], a2);
      float sp = softplus_f(a2);
      unsigned int uq = (unsigned int)ua[pp * 264 + d];
      unsigned short spb = f2bf(sp);
      udt[(p0 + pp) * 256 + d] = uq | ((unsigned int)spb << 16);
      float dtv = bf2f((unsigned int)spb);
      float uv  = bf2f(uq);
      float du = dtv * uv;
      sdt += dtv;
      const float* brow = &Bs_l[pp * 16];
      float4 b0 = *(const float4*)&brow[0];
      float4 b1 = *(const float4*)&brow[4];
      float4 b2 = *(const float4*)&brow[8];
      float4 b3 = *(const float4*)&brow[12];
      f32x2 B2[8] = {{b0.x,b0.y},{b0.z,b0.w},{b1.x,b1.y},{b1.z,b1.w},
                     {b2.x,b2.y},{b2.z,b2.w},{b3.x,b3.y},{b3.z,b3.w}};
      f32x2 du2 = {du, du};
      if (fast) {
        float e1 = __expf(-dtv);
        float e2 = e1 * e1;
        f32x2 dA = {e1, e2};
        f32x2 e22 = {e2, e2};
#pragma unroll
        for (int jj = 0; jj < 8; ++jj) {
          h2[jj] = dA * h2[jj] + du2 * B2[jj];
          dA = dA * e22;
        }
      } else {
#pragma unroll
        for (int j = 0; j < 16; ++j) {
          float dA = __expf(dtv * a[j]);
          h2[j >> 1][j & 1] = fmaf(dA, h2[j >> 1][j & 1], du * B2[j >> 1][j & 1]);
        }
      }
    }
#pragma unroll
    for (int j = 0; j < 16; ++j) {
      int o = (bc * 16 + j) * 256 + d;
      cP[o]  = f2bf(__expf(a[j] * sdt));
      cHe[o] = f2bf(h2[j >> 1][j & 1]);
    }
  }
}

// ---------------------------------------------------------------------------
// Hierarchical combine (NC=128, bf16): 512 thr = 64 sd x 8 segments of 16.
// ---------------------------------------------------------------------------
__global__ __launch_bounds__(512)
void scan_combine(unsigned short* __restrict__ cP, const unsigned short* __restrict__ cHe) {
  __shared__ float segP[64 * 9], segH[64 * 9], segS[64 * 9];
  const int t = threadIdx.x;
  const int sdl = t & 63, seg = t >> 6;
  const int blk = blockIdx.x;
  const int b = blk >> 6, grp = blk & 63;
  const int sd = (grp << 6) + sdl;
  const int base = b * NC * 4096 + sd;
  float Pacc = 1.f, Hacc = 0.f;
#pragma unroll
  for (int i = 0; i < 16; ++i) {
    int idx = base + (seg * 16 + i) * 4096;
    float p = bf2f((unsigned int)cP[idx]);
    float he = bf2f((unsigned int)cHe[idx]);
    Hacc = fmaf(p, Hacc, he);
    Pacc *= p;
  }
  segP[sdl * 9 + seg] = Pacc;
  segH[sdl * 9 + seg] = Hacc;
  __syncthreads();
  if (t < 64) {
    float hs = 0.f;
#pragma unroll
    for (int s2 = 0; s2 < 8; ++s2) {
      segS[t * 9 + s2] = hs;
      hs = fmaf(segP[t * 9 + s2], hs, segH[t * 9 + s2]);
    }
  }
  __syncthreads();
  float hs = segS[sdl * 9 + seg];
#pragma unroll
  for (int i = 0; i < 16; ++i) {
    int idx = base + (seg * 16 + i) * 4096;
    float p = bf2f((unsigned int)cP[idx]);
    float he = bf2f((unsigned int)cHe[idx]);
    cP[idx] = f2bf(hs);
    hs = fmaf(p, hs, he);
  }
}

// ---------------------------------------------------------------------------
// FUSED scan phase 3 + out_proj + LayerNorm + fc + ReLU.
// Block = 64 positions = 2 chunks scanned IN PARALLEL (thread t: chunk-half
// t>>8, channel d = t&255, all 16 states per lane). 32 serial iterations,
// no cross-lane shuffle (y reduced in-register), B/C LDS reads are
// wave-uniform broadcasts. Gated y -> smA (64x264 bf16), then the
// out_proj->LN->fc->ReLU epilogue runs in-kernel (waves 0-3).
// LDS: Bs 4K + Cs 4K + ya 33.8K + smB 34.8K = 76.6 KB -> 2 blocks/CU.
// ---------------------------------------------------------------------------
__global__ __launch_bounds__(512, 4)
void scan3_out_ln_fc(const unsigned int* __restrict__ udt,
                     const float* __restrict__ Bb, const float* __restrict__ Cb,
                     const float* __restrict__ alog, const unsigned short* __restrict__ hst,
                     const float* __restrict__ dsk,
                     const unsigned short* __restrict__ zsb,
                     const float* __restrict__ W,
                     const float* __restrict__ gamma, const float* __restrict__ beta,
                     const float* __restrict__ fcw, float* __restrict__ out) {
  __shared__ float Bs[CH2 * 16];             // 4 KB
  __shared__ float Cs[CH2 * 16];             // 4 KB
  __shared__ unsigned short smA[64 * 264];   // ya (stride 264); later hnb (stride 136)
  __shared__ unsigned short smB[128 * 136];  // ow halves (stride 264); later fcw (136)
  const int bc = blockIdx.x;
  const int b = bc >> 6, cc = bc & 63;
  const int t = threadIdx.x;
  const int l = t & 63, w = t >> 6;
  const int chh = t >> 8;                     // which of the 2 parallel chunks
  const int d = t & 255;                      // channel
  const int base = b * L_ + (cc << 1) * CH;   // 64-position tile start
  const int cbase = base + chh * CH;          // this chunk's start
  const int hc = b * NC + (cc << 1) + chh;    // h_start chunk index
  // stage B (threads 0-255) and C (threads 256-511): 64x16 floats each
  if (t < CH2 * 4)           ((float4*)Bs)[t]            = *(const float4*)&Bb[base * 16 + (t << 2)];
  else if (t < CH2 * 8)      ((float4*)Cs)[t - CH2 * 4]  = *(const float4*)&Cb[base * 16 + ((t - CH2 * 4) << 2)];
  // fast-path check: a_s == -(s+1) for all 16 states of this channel
  float a[16];
  bool okl = true;
#pragma unroll
  for (int j = 0; j < 16; ++j) {
    a[j] = -__expf(alog[d * 16 + j]);
    float tgt = (float)(j + 1);
    okl = okl && (fabsf(a[j] + tgt) <= 1e-3f * tgt);
  }
  const bool fast = (bool)__all((int)okl);
  const float dskv = dsk[d];
  f32x2 h2[8];
#pragma unroll
  for (int jj = 0; jj < 8; ++jj) {
    h2[jj][0] = bf2f((unsigned int)hst[(hc * 16 + (jj << 1)) * 256 + d]);
    h2[jj][1] = bf2f((unsigned int)hst[(hc * 16 + (jj << 1) + 1) * 256 + d]);
  }
  unsigned int wv0 = udt[cbase * 256 + d];
  unsigned int wv1 = udt[(cbase + 1) * 256 + d];
  unsigned short zv0 = zsb[cbase * 256 + d];
  unsigned short zv1 = zsb[(cbase + 1) * 256 + d];
  __syncthreads();
#pragma unroll 2
  for (int ll = 0; ll < CH; ++ll) {
    const int l2 = (ll + 2 < CH) ? ll + 2 : CH - 1;
    unsigned int wv2 = udt[(cbase + l2) * 256 + d];
    unsigned short zv2 = zsb[(cbase + l2) * 256 + d];
    const float* brow = &Bs[(chh * CH + ll) * 16];
    const float* crow = &Cs[(chh * CH + ll) * 16];
    float4 b0 = *(const float4*)&brow[0];
    float4 b1 = *(const float4*)&brow[4];
    float4 b2 = *(const float4*)&brow[8];
    float4 b3 = *(const float4*)&brow[12];
    float4 c0 = *(const float4*)&crow[0];
    float4 c1 = *(const float4*)&crow[4];
    float4 c2 = *(const float4*)&crow[8];
    float4 c3 = *(const float4*)&crow[12];
    float uv  = bf2f(wv0 & 0xFFFFu);
    float dtv = bf2f(wv0 >> 16);
    f32x2 B2[8] = {{b0.x,b0.y},{b0.z,b0.w},{b1.x,b1.y},{b1.z,b1.w},
                   {b2.x,b2.y},{b2.z,b2.w},{b3.x,b3.y},{b3.z,b3.w}};
    f32x2 C2[8] = {{c0.x,c0.y},{c0.z,c0.w},{c1.x,c1.y},{c1.z,c1.w},
                   {c2.x,c2.y},{c2.z,c2.w},{c3.x,c3.y},{c3.z,c3.w}};
    float du = dtv * uv;
    f32x2 du2 = {du, du};
    f32x2 y2 = {0.f, 0.f};
    if (fast) {
      float e1 = __expf(-dtv);
      float e2 = e1 * e1;
      f32x2 dA = {e1, e2};        // decay for states 0,1 = e1^1, e1^2
      f32x2 e22 = {e2, e2};
#pragma unroll
      for (int jj = 0; jj < 8; ++jj) {
        h2[jj] = dA * h2[jj] + du2 * B2[jj];
        y2 = y2 + h2[jj] * C2[jj];
        dA = dA * e22;
      }
    } else {
#pragma unroll
      for (int j = 0; j < 16; ++j) {
        float dA = __expf(dtv * a[j]);
        float hh = fmaf(dA, h2[j >> 1][j & 1], du * B2[j >> 1][j & 1]);
        h2[j >> 1][j & 1] = hh;
        y2[j & 1] = fmaf(hh, C2[j >> 1][j & 1], y2[j & 1]);
      }
    }
    float y = y2.x + y2.y;
    float zs = bf2f((unsigned int)zv0);
    smA[(chh * CH + ll) * 264 + d] = f2bf(fmaf(uv, dskv, y) * zs);   // ya, bf16
    wv0 = wv1; wv1 = wv2; zv0 = zv1; zv1 = zv2;
  }
  // ---------------- epilogue: out_proj -> LN -> fc -> ReLU ----------------
  const int q = l >> 4, col = l & 15;
  ffrag acc[2][4];
  for (int nt2 = 0; nt2 < 2; ++nt2) {
    __syncthreads();           // iter0: ya complete; iterN: prior MFMA reads done
    for (int i = t; i < 64 * 64; i += 512) {
      int row = i >> 6, c4 = i & 63;
      float4 wv = *(const float4*)&W[((nt2 << 6) + row) * 256 + (c4 << 2)];
      uint2 wp = {f2bf2(wv.x, wv.y), f2bf2(wv.z, wv.w)};
      *(uint2*)&smB[row * 264 + (c4 << 2)] = wp;
    }
    __syncthreads();
    if (t < 256) {
#pragma unroll
      for (int nt = 0; nt < 4; ++nt) acc[nt2][nt] = (ffrag){0.f, 0.f, 0.f, 0.f};
#pragma unroll
      for (int s8 = 0; s8 < 8; ++s8) {
        int k0 = s8 * 32 + q * 8;
        bfrag af = *(const bfrag*)&smA[((w << 4) + col) * 264 + k0];
#pragma unroll
        for (int nt = 0; nt < 4; ++nt) {
          bfrag bf_ = *(const bfrag*)&smB[((nt << 4) + col) * 264 + k0];
          acc[nt2][nt] = __builtin_amdgcn_mfma_f32_16x16x32_bf16(af, bf_, acc[nt2][nt], 0, 0, 0);
        }
      }
    }
  }
  float mu[4], rs[4];
  if (t < 256) {
#pragma unroll
    for (int i = 0; i < 4; ++i) {
      float s1 = 0.f, s2 = 0.f;
#pragma unroll
      for (int nt2 = 0; nt2 < 2; ++nt2)
#pragma unroll
        for (int nt = 0; nt < 4; ++nt) {
          float v = acc[nt2][nt][i];
          s1 += v; s2 = fmaf(v, v, s2);
        }
      s1 += __shfl_xor(s1, 1); s2 += __shfl_xor(s2, 1);
      s1 += __shfl_xor(s1, 2); s2 += __shfl_xor(s2, 2);
      s1 += __shfl_xor(s1, 4); s2 += __shfl_xor(s2, 4);
      s1 += __shfl_xor(s1, 8); s2 += __shfl_xor(s2, 8);
      mu[i] = s1 * (1.f / DM);
      float var = s2 * (1.f / DM) - mu[i] * mu[i];
      rs[i] = rsqrtf(var + 1e-5f);
    }
  }
  __syncthreads();   // all MFMA LDS reads done before overlaying smA/smB
  if (t < 256) {
#pragma unroll
    for (int nt2 = 0; nt2 < 2; ++nt2)
#pragma unroll
      for (int nt = 0; nt < 4; ++nt) {
        int n = (nt2 << 6) + (nt << 4) + col;
        float g = gamma[n], be = beta[n];
#pragma unroll
        for (int i = 0; i < 4; ++i) {
          int r = (w << 4) + (q << 2) + i;
          smA[r * 136 + n] = f2bf(fmaf((acc[nt2][nt][i] - mu[i]) * rs[i], g, be));
        }
      }
  }
  for (int i = t; i < 128 * 32; i += 512) {
    int row = i >> 5, c4 = i & 31;
    float4 wv = *(const float4*)&fcw[row * 128 + (c4 << 2)];
    uint2 wp = {f2bf2(wv.x, wv.y), f2bf2(wv.z, wv.w)};
    *(uint2*)&smB[row * 136 + (c4 << 2)] = wp;
  }
  __syncthreads();
  if (t < 256) {
    ffrag a2[8] = {{0.f,0.f,0.f,0.f},{0.f,0.f,0.f,0.f},{0.f,0.f,0.f,0.f},{0.f,0.f,0.f,0.f},
                   {0.f,0.f,0.f,0.f},{0.f,0.f,0.f,0.f},{0.f,0.f,0.f,0.f},{0.f,0.f,0.f,0.f}};
#pragma unroll
    for (int s8 = 0; s8 < 4; ++s8) {
      int k0 = s8 * 32 + q * 8;
      bfrag af = *(const bfrag*)&smA[((w << 4) + col) * 136 + k0];
#pragma unroll
      for (int nt = 0; nt < 8; ++nt) {
        bfrag bf_ = *(const bfrag*)&smB[((nt << 4) + col) * 136 + k0];
        a2[nt] = __builtin_amdgcn_mfma_f32_16x16x32_bf16(af, bf_, a2[nt], 0, 0, 0);
      }
    }
#pragma unroll
    for (int nt = 0; nt < 8; ++nt)
#pragma unroll
      for (int i = 0; i < 4; ++i) {
        int ml = (w << 4) + (q << 2) + i;
        out[(base + ml) * 128 + (nt << 4) + col] = fmaxf(a2[nt][i], 0.f);
      }
  }
}

extern "C" void kernel_launch(void* const* d_in, const int* in_sizes, int n_in,
                              void* d_out, int out_size, void* d_ws, size_t ws_size,
                              hipStream_t stream) {
  (void)in_sizes; (void)n_in; (void)out_size; (void)ws_size;
  const float* s    = (const float*)d_in[0];
  const float* w_in = (const float*)d_in[1];
  const float* cw   = (const float*)d_in[2];
  const float* cb   = (const float*)d_in[3];
  const float* xw   = (const float*)d_in[4];
  const float* dtw  = (const float*)d_in[5];
  const float* dtpb = (const float*)d_in[6];
  const float* alog = (const float*)d_in[7];
  const float* dsk  = (const float*)d_in[8];
  const float* ow   = (const float*)d_in[9];
  const float* gam  = (const float*)d_in[10];
  const float* bet  = (const float*)d_in[11];
  const float* fcw  = (const float*)d_in[12];
  float* out = (float*)d_out;
  float* ws  = (float*)d_ws;

  // float-unit offsets; all regions disjoint (audited):
  unsigned short* zsb  = (unsigned short*)(ws + 4194304);     // [4194304, 8388608)
  unsigned int*   udt  = (unsigned int*)(ws + 8388608);       // [8388608, 16777216)
  float*          Bb   = ws + 16777216;                       // [16777216, 17301504)
  float*          Cb   = ws + 17301504;                       // [17301504, 17825792)
  unsigned short* cP   = (unsigned short*)(ws + 17825792);    // [17825792, 19922944)
  unsigned short* cHe  = (unsigned short*)(ws + 19922944);    // [19922944, 22020096)

  // 1. MEGA-FUSED: in_proj + conv/silu + x_proj + dt_proj + scan phase 1
  xproj_dtproj<<<512, 512, 0, stream>>>(s, w_in, xw, dtw, dtpb, cw, cb, alog,
                                        Bb, Cb, udt, zsb, cP, cHe);
  // 2. inter-chunk combine
  scan_combine<<<512, 512, 0, stream>>>(cP, cHe);
  // 3. FUSED scan phase 3 (2 parallel chunks/block) + out_proj + LN + fc + ReLU
  scan3_out_ln_fc<<<B_ * NC / 2, 512, 0, stream>>>(udt, Bb, Cb, alog, cP, dsk, zsb,
                                                   ow, gam, bet, fcw, out);
}